// Round 7
// baseline (201.037 us; speedup 1.0000x reference)
//
#include <hip/hip_runtime.h>

// ---------------- constants for this problem ----------------
// N_NODES=100000, N_EDGES=1600000, IN_FEATS=128, H=4, D=32, HD=128, NUM_ETYPES=8, DROP_BLOCKS=4
// Bucket = 512 consecutive dst nodes (nbuk = ceil(N/512) = 196).
// csr2 entry: src[0:17) | etype[17:20) | (dst&511)[20:29)
// csr  entry: src[0:20) | etype[20:23)

typedef short short8 __attribute__((ext_vector_type(8)));
typedef unsigned short ushort8 __attribute__((ext_vector_type(8)));
typedef float f32x4 __attribute__((ext_vector_type(4)));

__device__ inline unsigned short f2bf(float x) {
    unsigned u = __builtin_bit_cast(unsigned, x);
    u += 0x7FFFu + ((u >> 16) & 1u);   // RNE
    return (unsigned short)(u >> 16);
}

// K1: coarse bucket histogram (196 buckets of 512 nodes)
__global__ __launch_bounds__(256) void k_bcnt(const int* __restrict__ dst,
                                              unsigned* __restrict__ gcnt, int E) {
    __shared__ unsigned l[256];
    int tid = threadIdx.x;
    l[tid] = 0;
    __syncthreads();
    int base = blockIdx.x * 2048;
#pragma unroll
    for (int j = 0; j < 8; ++j) {
        int e = base + j * 256 + tid;
        if (e < E) atomicAdd(&l[(unsigned)dst[e] >> 9], 1u);
    }
    __syncthreads();
    if (l[tid]) atomicAdd(&gcnt[tid], l[tid]);
}

// K2: exclusive scan of bucket counts (single block, 256 >= nbuk)
__global__ __launch_bounds__(256) void k_bscan(const unsigned* __restrict__ gcnt,
                                               unsigned* __restrict__ gbase,
                                               unsigned* __restrict__ gcur) {
    __shared__ unsigned s[256];
    int t = threadIdx.x;
    unsigned orig = gcnt[t];
    s[t] = orig;
    __syncthreads();
    for (int of = 1; of < 256; of <<= 1) {
        unsigned v = (t >= of) ? s[t - of] : 0u;
        __syncthreads();
        s[t] += v;
        __syncthreads();
    }
    unsigned eb = s[t] - orig;
    gbase[t] = eb;
    gcur[t] = eb;
}

// K3: LDS-staged partition: group 4096-edge chunks by bucket in LDS, reserve
// per-bucket global space (1 atomic per block-bucket), flush coalesced.
__global__ __launch_bounds__(256) void k_part(const int* __restrict__ src,
                                              const int* __restrict__ dst,
                                              const int* __restrict__ ef,
                                              unsigned* __restrict__ gcur,
                                              unsigned* __restrict__ csr2,
                                              int E, int nbuk) {
    __shared__ unsigned lcnt[256];
    __shared__ unsigned lbase[256];
    __shared__ unsigned lcur[256];
    __shared__ unsigned gw2[256];
    __shared__ unsigned stp[4096];
    __shared__ unsigned short stb[4096];
    int tid = threadIdx.x;
    lcnt[tid] = 0;
    __syncthreads();

    int cb = blockIdx.x * 4096;
    int cc = E - cb; if (cc > 4096) cc = 4096;

    unsigned pay[16];
    unsigned short bk[16];
#pragma unroll
    for (int j = 0; j < 16; ++j) {
        int idx = j * 256 + tid;
        if (idx < cc) {
            int e = cb + idx;
            unsigned d = (unsigned)dst[e];
            pay[j] = (unsigned)src[e] | ((unsigned)ef[e] << 17) | ((d & 511u) << 20);
            bk[j] = (unsigned short)(d >> 9);
            atomicAdd(&lcnt[bk[j]], 1u);
        }
    }
    __syncthreads();
    // scan lcnt -> exclusive lbase
    lbase[tid] = lcnt[tid];
    __syncthreads();
    for (int of = 1; of < 256; of <<= 1) {
        unsigned v = (tid >= of) ? lbase[tid - of] : 0u;
        __syncthreads();
        lbase[tid] += v;
        __syncthreads();
    }
    unsigned eb = lbase[tid] - lcnt[tid];
    __syncthreads();
    lbase[tid] = eb;
    lcur[tid] = eb;
    __syncthreads();
    // LDS scatter: group by bucket
#pragma unroll
    for (int j = 0; j < 16; ++j) {
        int idx = j * 256 + tid;
        if (idx < cc) {
            unsigned lpos = atomicAdd(&lcur[bk[j]], 1u);
            stp[lpos] = pay[j];
            stb[lpos] = bk[j];
        }
    }
    // reserve global space
    if (tid < nbuk && lcnt[tid]) gw2[tid] = atomicAdd(&gcur[tid], lcnt[tid]);
    __syncthreads();
    // coalesced flush
#pragma unroll
    for (int j = 0; j < 16; ++j) {
        int i = j * 256 + tid;
        if (i < cc) {
            unsigned b = stb[i];
            csr2[gw2[b] + (i - lbase[b])] = stp[i];
        }
    }
}

// K4: per-bucket: count (node,etype), scan node degrees -> offs/deg/stats,
// then counting-sort into final node-grouped CSR (L2-hot region).
__global__ __launch_bounds__(256) void k_bsort2(const unsigned* __restrict__ csr2,
                                                const unsigned* __restrict__ gbase,
                                                const unsigned* __restrict__ gcnt,
                                                const float* __restrict__ emb,
                                                unsigned* __restrict__ csr,
                                                unsigned* __restrict__ offs,
                                                unsigned* __restrict__ deg,
                                                float* __restrict__ stats, int N) {
    __shared__ unsigned cnt8[512 * 8];   // 16 KB
    __shared__ unsigned degL[512];
    __shared__ unsigned offsL[512];
    __shared__ unsigned curL[512];
    __shared__ unsigned tmp[256];
    __shared__ float se[32];
    int b = blockIdx.x, tid = threadIdx.x;
    if (tid < 32) se[tid] = emb[tid];
#pragma unroll
    for (int i = 0; i < 16; ++i) cnt8[i * 256 + tid] = 0u;
    __syncthreads();
    unsigned r0 = gbase[b], r1 = r0 + gcnt[b];
    for (unsigned i = r0 + tid; i < r1; i += 256) {
        unsigned en = csr2[i];
        atomicAdd(&cnt8[((en >> 20) & 511u) * 8u + ((en >> 17) & 7u)], 1u);
    }
    __syncthreads();
    int n0 = tid * 2, n1 = tid * 2 + 1;
    unsigned d0 = 0, d1 = 0;
#pragma unroll
    for (int k = 0; k < 8; ++k) { d0 += cnt8[n0 * 8 + k]; d1 += cnt8[n1 * 8 + k]; }
    degL[n0] = d0; degL[n1] = d1;
    tmp[tid] = d0 + d1;
    __syncthreads();
    for (int of = 1; of < 256; of <<= 1) {
        unsigned v = (tid >= of) ? tmp[tid - of] : 0u;
        __syncthreads();
        tmp[tid] += v;
        __syncthreads();
    }
    unsigned eb = tmp[tid] - (d0 + d1);
    offsL[n0] = eb;        curL[n0] = eb;
    offsL[n1] = eb + d0;   curL[n1] = eb + d0;
    // per-node outputs + fused softmax stats
#pragma unroll
    for (int q = 0; q < 2; ++q) {
        int nl = tid * 2 + q;
        int gn = b * 512 + nl;
        if (gn < N) {
            offs[gn] = r0 + offsL[nl];
            unsigned dg = degL[nl];
            deg[gn] = dg;
            const unsigned* c = &cnt8[nl * 8];
#pragma unroll
            for (int h = 0; h < 4; ++h) {
                float m = -3.4e38f;
#pragma unroll
                for (int tt = 0; tt < 8; ++tt)
                    if (c[tt]) m = fmaxf(m, se[tt * 4 + h]);
                float s = 0.f;
#pragma unroll
                for (int tt = 0; tt < 8; ++tt)
                    if (c[tt]) s += (float)c[tt] * expf(se[tt * 4 + h] - m);
                stats[(size_t)gn * 8 + h] = m;
                stats[(size_t)gn * 8 + 4 + h] = dg ? (1.0f / s) : 0.0f;
            }
        }
    }
    __syncthreads();
    // counting-sort scatter within the (L2-hot) bucket region
    for (unsigned i = r0 + tid; i < r1; i += 256) {
        unsigned en = csr2[i];
        unsigned nlo = (en >> 20) & 511u;
        unsigned tt = (en >> 17) & 7u;
        unsigned pos = r0 + atomicAdd(&curL[nlo], 1u);
        csr[pos] = (en & 0x1FFFFu) | (tt << 20);
    }
}

// K5: attn_out (E, H, 4, 1) — thread per edge, 64 B contiguous store
__global__ __launch_bounds__(256) void k_attn_out(const int* __restrict__ e_feat,
                                                  const int* __restrict__ dst,
                                                  const float* __restrict__ emb,
                                                  const float* __restrict__ stats,
                                                  float4* __restrict__ ao, int E) {
    int e = blockIdx.x * 256 + threadIdx.x;
    if (e >= E) return;
    int tt = e_feat[e];
    int d = dst[e];
    const float4* st4 = (const float4*)(stats + (size_t)d * 8);
    float4 m4 = st4[0], i4 = st4[1];
    float4 ee = *(const float4*)(emb + tt * 4);
    float a0 = expf(ee.x - m4.x) * i4.x;
    float a1 = expf(ee.y - m4.y) * i4.y;
    float a2 = expf(ee.z - m4.z) * i4.z;
    float a3 = expf(ee.w - m4.w) * i4.w;
    float4* p = ao + (size_t)e * 4;
    p[0] = make_float4(a0, a0, a0, a0);
    p[1] = make_float4(a1, a1, a1, a1);
    p[2] = make_float4(a2, a2, a2, a2);
    p[3] = make_float4(a3, a3, a3, a3);
}

// K6: ft = feat @ W^T via bf16 MFMA; A direct from global; W staged in LDS
// (swizzled). Epilogue goes through LDS (reusing the W buffer) so global
// stores are wide & contiguous (wave writes 16 full rows = 4 KB per instr).
__global__ __launch_bounds__(256) void k_gemm_mfma(const float* __restrict__ feat,
                                                   const float* __restrict__ W,
                                                   unsigned short* __restrict__ ftb, int N) {
    __shared__ unsigned short Sb[128 * 136];  // 34 KB: W (swizzled) then out-tile
    int tid = threadIdx.x;
    int row0 = blockIdx.x * 128;

    // ---- stage W: fp32 -> bf16, swizzled (byte ^= (row&7)<<4) ----
#pragma unroll
    for (int it = 0; it < 16; ++it) {
        int i = it * 1024 + tid * 4;
        int r = i >> 7, c = i & 127;
        unsigned swz = (unsigned)((r & 7) << 4);
        float4 w4 = *(const float4*)(W + i);
        ushort4 wb;
        wb.x = f2bf(w4.x); wb.y = f2bf(w4.y); wb.z = f2bf(w4.z); wb.w = f2bf(w4.w);
        *(ushort4*)((char*)Sb + (((unsigned)(r * 256 + c * 2)) ^ swz)) = wb;
    }
    __syncthreads();

    int wv = tid >> 6, lane = tid & 63;
    int rl = lane & 15;
    unsigned swz = (unsigned)((lane & 7) << 4);
    int kq = (lane >> 4) * 16;          // LDS byte offset of this lane's k-octet
    int ko = (lane >> 4) * 8;           // element offset of k-octet

    int ra0 = row0 + wv * 32 + rl;
    int ra1 = ra0 + 16;
    bool v0 = ra0 < N, v1 = ra1 < N;
    const float* ap0 = feat + (size_t)ra0 * 128 + ko;
    const float* ap1 = feat + (size_t)ra1 * 128 + ko;

    f32x4 acc[2][8];
#pragma unroll
    for (int rt = 0; rt < 2; ++rt)
#pragma unroll
        for (int jt = 0; jt < 8; ++jt)
            acc[rt][jt] = (f32x4){0.f, 0.f, 0.f, 0.f};

    const char* Bb = (const char*)Sb;
#pragma unroll
    for (int kk = 0; kk < 4; ++kk) {
        int kb = kk * 64 + kq;
        short8 a[2], bfr[8];
#pragma unroll
        for (int rt = 0; rt < 2; ++rt) {
            const float* ap = rt ? ap1 : ap0;
            bool v = rt ? v1 : v0;
            float4 lo = make_float4(0.f, 0.f, 0.f, 0.f), hi = lo;
            if (v) { lo = *(const float4*)(ap + kk * 32); hi = *(const float4*)(ap + kk * 32 + 4); }
            short8 t;
            t[0] = (short)f2bf(lo.x); t[1] = (short)f2bf(lo.y);
            t[2] = (short)f2bf(lo.z); t[3] = (short)f2bf(lo.w);
            t[4] = (short)f2bf(hi.x); t[5] = (short)f2bf(hi.y);
            t[6] = (short)f2bf(hi.z); t[7] = (short)f2bf(hi.w);
            a[rt] = t;
        }
#pragma unroll
        for (int jt = 0; jt < 8; ++jt)
            bfr[jt] = *(const short8*)(Bb + (((unsigned)((jt * 16 + rl) * 256 + kb)) ^ swz));
#pragma unroll
        for (int rt = 0; rt < 2; ++rt)
#pragma unroll
            for (int jt = 0; jt < 8; ++jt)
                acc[rt][jt] = __builtin_amdgcn_mfma_f32_16x16x32_bf16(a[rt], bfr[jt], acc[rt][jt], 0, 0, 0);
    }

    // ---- epilogue via LDS: W buffer is dead; overwrite with out tile ----
    __syncthreads();
#pragma unroll
    for (int rt = 0; rt < 2; ++rt) {
        int rbase = wv * 32 + rt * 16 + ((lane >> 4) << 2);
#pragma unroll
        for (int jt = 0; jt < 8; ++jt) {
            int col = jt * 16 + rl;
#pragma unroll
            for (int rg = 0; rg < 4; ++rg)
                Sb[(rbase + rg) * 136 + col] = f2bf(acc[rt][jt][rg]);
        }
    }
    __syncthreads();
    // read back rows, wide contiguous stores: wave covers 16 full rows (4 KB)
#pragma unroll
    for (int g = 0; g < 8; ++g) {
        int rloc = g * 16 + (tid >> 4);
        int cc = (tid & 15) * 8;
        int gr = row0 + rloc;
        if (gr < N) {
            ushort8 v = *(const ushort8*)(&Sb[rloc * 136 + cc]);
            *(ushort8*)(ftb + (size_t)gr * 128 + cc) = v;
        }
    }
}

// K7: aggregate: wave per node; csr chunk loaded once per 64 edges (coalesced),
// entries broadcast via shfl -> independent back-to-back ft row loads.
__global__ __launch_bounds__(256) void k_agg(const unsigned* __restrict__ csr,
                                             const unsigned* __restrict__ offs,
                                             const unsigned* __restrict__ deg,
                                             const float* __restrict__ stats,
                                             const float* __restrict__ emb,
                                             const unsigned* __restrict__ ftu,  // bf16 pairs
                                             float* __restrict__ rst, int N) {
    __shared__ float wl[4 * 32];
    int tid = threadIdx.x;
    int wv = tid >> 6, lane = tid & 63;
    int n = blockIdx.x * 4 + wv;
    n = __builtin_amdgcn_readfirstlane(n);
    if (n < N && lane < 32) {
        int tt = lane >> 2, hh = lane & 3;
        float m = stats[(size_t)n * 8 + hh];
        float is = stats[(size_t)n * 8 + 4 + hh];
        wl[wv * 32 + lane] = expf(emb[tt * 4 + hh] - m) * is;
    }
    __syncthreads();
    if (n >= N) return;
    unsigned o = offs[n], dg = deg[n];
    int h = lane >> 4;
    const float* wlh = wl + wv * 32 + h;
    float accx = 0.f, accy = 0.f;
    for (unsigned kb = 0; kb < dg; kb += 64) {
        unsigned rem = dg - kb; if (rem > 64) rem = 64;
        unsigned centry = 0;
        if (lane < (int)rem) centry = csr[o + kb + lane];
        unsigned j = 0;
        for (; j + 8 <= rem; j += 8) {
            unsigned f[8]; float a[8];
#pragma unroll
            for (int jj = 0; jj < 8; ++jj) {
                unsigned e = __shfl(centry, (int)(j + jj), 64);
                f[jj] = ftu[(size_t)(e & 0xFFFFFu) * 64 + lane];
                a[jj] = wlh[(e >> 20) * 4];
            }
#pragma unroll
            for (int jj = 0; jj < 8; ++jj) {
                accx = fmaf(a[jj], __builtin_bit_cast(float, f[jj] << 16), accx);
                accy = fmaf(a[jj], __builtin_bit_cast(float, f[jj] & 0xFFFF0000u), accy);
            }
        }
        for (; j < rem; ++j) {
            unsigned e = __shfl(centry, (int)j, 64);
            unsigned f0 = ftu[(size_t)(e & 0xFFFFFu) * 64 + lane];
            float a0 = wlh[(e >> 20) * 4];
            accx = fmaf(a0, __builtin_bit_cast(float, f0 << 16), accx);
            accy = fmaf(a0, __builtin_bit_cast(float, f0 & 0xFFFF0000u), accy);
        }
    }
    ((float2*)rst)[(size_t)n * 64 + lane] = make_float2(accx, accy);
}

extern "C" void kernel_launch(void* const* d_in, const int* in_sizes, int n_in,
                              void* d_out, int out_size, void* d_ws, size_t ws_size,
                              hipStream_t stream) {
    const float* feat = (const float*)d_in[0];
    const float* W = (const float*)d_in[1];
    const float* emb = (const float*)d_in[2];
    const int* e_feat = (const int*)d_in[3];
    const int* src = (const int*)d_in[4];
    const int* dst = (const int*)d_in[5];
    int N = in_sizes[0] / 128;
    int E = in_sizes[3];
    int nbuk = (N + 511) >> 9;

    char* ws = (char*)d_ws;
    size_t off = 0;
    auto alloc = [&](size_t bytes) {
        void* p = ws + off;
        off = (off + bytes + 255) & ~(size_t)255;
        return p;
    };
    unsigned short* ftb = (unsigned short*)alloc((size_t)N * 128 * 2);
    float* stats = (float*)alloc((size_t)N * 8 * 4);
    unsigned* deg = (unsigned*)alloc((size_t)N * 4);
    unsigned* offs = (unsigned*)alloc((size_t)N * 4);
    unsigned* csr = (unsigned*)alloc((size_t)E * 4);
    unsigned* csr2 = (unsigned*)alloc((size_t)E * 4);
    unsigned* gcnt = (unsigned*)alloc(256 * 4);
    unsigned* gbase = (unsigned*)alloc(256 * 4);
    unsigned* gcur = (unsigned*)alloc(256 * 4);

    float* rst = (float*)d_out;
    float4* ao = (float4*)((float*)d_out + (size_t)N * 128);

    hipMemsetAsync(gcnt, 0, 256 * 4, stream);

    k_bcnt<<<(E + 2047) / 2048, 256, 0, stream>>>(dst, gcnt, E);
    k_bscan<<<1, 256, 0, stream>>>(gcnt, gbase, gcur);
    k_part<<<(E + 4095) / 4096, 256, 0, stream>>>(src, dst, e_feat, gcur, csr2, E, nbuk);
    k_bsort2<<<nbuk, 256, 0, stream>>>(csr2, gbase, gcnt, emb, csr, offs, deg, stats, N);
    k_gemm_mfma<<<(N + 127) / 128, 256, 0, stream>>>(feat, W, ftb, N);
    k_attn_out<<<(E + 255) / 256, 256, 0, stream>>>(e_feat, dst, emb, stats, ao, E);
    k_agg<<<(N + 3) / 4, 256, 0, stream>>>(csr, offs, deg, stats, emb, (const unsigned*)ftb, rst, N);
}

// Round 8
// 200.049 us; speedup vs baseline: 1.0049x; 1.0049x over previous
//
#include <hip/hip_runtime.h>

// ---------------- constants for this problem ----------------
// N_NODES=100000, N_EDGES=1600000, IN_FEATS=128, H=4, D=32, HD=128, NUM_ETYPES=8, DROP_BLOCKS=4
// Bucket = 512 consecutive dst nodes (nbuk = ceil(N/512) = 196).
// csr2 entry: src[0:17) | etype[17:20) | (dst&511)[20:29)
// csr  entry: src[0:20) | etype[20:23)

typedef short short8 __attribute__((ext_vector_type(8)));
typedef unsigned short ushort8 __attribute__((ext_vector_type(8)));
typedef float f32x4 __attribute__((ext_vector_type(4)));

__device__ inline unsigned short f2bf(float x) {
    unsigned u = __builtin_bit_cast(unsigned, x);
    u += 0x7FFFu + ((u >> 16) & 1u);   // RNE
    return (unsigned short)(u >> 16);
}

// K0: one-shot fp32 -> bf16 conversion of feat and W into workspace
__global__ __launch_bounds__(256) void k_cvt(const float* __restrict__ feat,
                                             const float* __restrict__ W,
                                             unsigned short* __restrict__ featb,
                                             unsigned short* __restrict__ Wb,
                                             long nf, long nw) {
    long i = ((long)blockIdx.x * 256 + threadIdx.x) * 8;
    const float* sp; unsigned short* dp; long j;
    if (i < nf) { sp = feat; dp = featb; j = i; }
    else { j = i - nf; if (j >= nw) return; sp = W; dp = Wb; }
    float4 lo = *(const float4*)(sp + j);
    float4 hi = *(const float4*)(sp + j + 4);
    ushort8 v;
    v[0] = f2bf(lo.x); v[1] = f2bf(lo.y); v[2] = f2bf(lo.z); v[3] = f2bf(lo.w);
    v[4] = f2bf(hi.x); v[5] = f2bf(hi.y); v[6] = f2bf(hi.z); v[7] = f2bf(hi.w);
    *(ushort8*)(dp + j) = v;
}

// K1: coarse bucket histogram (196 buckets of 512 nodes)
__global__ __launch_bounds__(256) void k_bcnt(const int* __restrict__ dst,
                                              unsigned* __restrict__ gcnt, int E) {
    __shared__ unsigned l[256];
    int tid = threadIdx.x;
    l[tid] = 0;
    __syncthreads();
    int base = blockIdx.x * 2048;
#pragma unroll
    for (int j = 0; j < 8; ++j) {
        int e = base + j * 256 + tid;
        if (e < E) atomicAdd(&l[(unsigned)dst[e] >> 9], 1u);
    }
    __syncthreads();
    if (l[tid]) atomicAdd(&gcnt[tid], l[tid]);
}

// K2: exclusive scan of bucket counts (single block, 256 >= nbuk)
__global__ __launch_bounds__(256) void k_bscan(const unsigned* __restrict__ gcnt,
                                               unsigned* __restrict__ gbase,
                                               unsigned* __restrict__ gcur) {
    __shared__ unsigned s[256];
    int t = threadIdx.x;
    unsigned orig = gcnt[t];
    s[t] = orig;
    __syncthreads();
    for (int of = 1; of < 256; of <<= 1) {
        unsigned v = (t >= of) ? s[t - of] : 0u;
        __syncthreads();
        s[t] += v;
        __syncthreads();
    }
    unsigned eb = s[t] - orig;
    gbase[t] = eb;
    gcur[t] = eb;
}

// K3: LDS-staged partition: group 4096-edge chunks by bucket in LDS, reserve
// per-bucket global space (1 atomic per block-bucket), flush coalesced.
__global__ __launch_bounds__(256) void k_part(const int* __restrict__ src,
                                              const int* __restrict__ dst,
                                              const int* __restrict__ ef,
                                              unsigned* __restrict__ gcur,
                                              unsigned* __restrict__ csr2,
                                              int E, int nbuk) {
    __shared__ unsigned lcnt[256];
    __shared__ unsigned lbase[256];
    __shared__ unsigned lcur[256];
    __shared__ unsigned gw2[256];
    __shared__ unsigned stp[4096];
    __shared__ unsigned short stb[4096];
    int tid = threadIdx.x;
    lcnt[tid] = 0;
    __syncthreads();

    int cb = blockIdx.x * 4096;
    int cc = E - cb; if (cc > 4096) cc = 4096;

    unsigned pay[16];
    unsigned short bk[16];
#pragma unroll
    for (int j = 0; j < 16; ++j) {
        int idx = j * 256 + tid;
        if (idx < cc) {
            int e = cb + idx;
            unsigned d = (unsigned)dst[e];
            pay[j] = (unsigned)src[e] | ((unsigned)ef[e] << 17) | ((d & 511u) << 20);
            bk[j] = (unsigned short)(d >> 9);
            atomicAdd(&lcnt[bk[j]], 1u);
        }
    }
    __syncthreads();
    lbase[tid] = lcnt[tid];
    __syncthreads();
    for (int of = 1; of < 256; of <<= 1) {
        unsigned v = (tid >= of) ? lbase[tid - of] : 0u;
        __syncthreads();
        lbase[tid] += v;
        __syncthreads();
    }
    unsigned eb = lbase[tid] - lcnt[tid];
    __syncthreads();
    lbase[tid] = eb;
    lcur[tid] = eb;
    __syncthreads();
#pragma unroll
    for (int j = 0; j < 16; ++j) {
        int idx = j * 256 + tid;
        if (idx < cc) {
            unsigned lpos = atomicAdd(&lcur[bk[j]], 1u);
            stp[lpos] = pay[j];
            stb[lpos] = bk[j];
        }
    }
    if (tid < nbuk && lcnt[tid]) gw2[tid] = atomicAdd(&gcur[tid], lcnt[tid]);
    __syncthreads();
#pragma unroll
    for (int j = 0; j < 16; ++j) {
        int i = j * 256 + tid;
        if (i < cc) {
            unsigned b = stb[i];
            csr2[gw2[b] + (i - lbase[b])] = stp[i];
        }
    }
}

// K4: per-bucket: count (node,etype), scan node degrees -> offs/deg/stats,
// then counting-sort into final node-grouped CSR (L2-hot region).
__global__ __launch_bounds__(256) void k_bsort2(const unsigned* __restrict__ csr2,
                                                const unsigned* __restrict__ gbase,
                                                const unsigned* __restrict__ gcnt,
                                                const float* __restrict__ emb,
                                                unsigned* __restrict__ csr,
                                                unsigned* __restrict__ offs,
                                                unsigned* __restrict__ deg,
                                                float* __restrict__ stats, int N) {
    __shared__ unsigned cnt8[512 * 8];   // 16 KB
    __shared__ unsigned degL[512];
    __shared__ unsigned offsL[512];
    __shared__ unsigned curL[512];
    __shared__ unsigned tmp[256];
    __shared__ float se[32];
    int b = blockIdx.x, tid = threadIdx.x;
    if (tid < 32) se[tid] = emb[tid];
#pragma unroll
    for (int i = 0; i < 16; ++i) cnt8[i * 256 + tid] = 0u;
    __syncthreads();
    unsigned r0 = gbase[b], r1 = r0 + gcnt[b];
    for (unsigned i = r0 + tid; i < r1; i += 256) {
        unsigned en = csr2[i];
        atomicAdd(&cnt8[((en >> 20) & 511u) * 8u + ((en >> 17) & 7u)], 1u);
    }
    __syncthreads();
    int n0 = tid * 2, n1 = tid * 2 + 1;
    unsigned d0 = 0, d1 = 0;
#pragma unroll
    for (int k = 0; k < 8; ++k) { d0 += cnt8[n0 * 8 + k]; d1 += cnt8[n1 * 8 + k]; }
    degL[n0] = d0; degL[n1] = d1;
    tmp[tid] = d0 + d1;
    __syncthreads();
    for (int of = 1; of < 256; of <<= 1) {
        unsigned v = (tid >= of) ? tmp[tid - of] : 0u;
        __syncthreads();
        tmp[tid] += v;
        __syncthreads();
    }
    unsigned eb = tmp[tid] - (d0 + d1);
    offsL[n0] = eb;        curL[n0] = eb;
    offsL[n1] = eb + d0;   curL[n1] = eb + d0;
#pragma unroll
    for (int q = 0; q < 2; ++q) {
        int nl = tid * 2 + q;
        int gn = b * 512 + nl;
        if (gn < N) {
            offs[gn] = r0 + offsL[nl];
            unsigned dg = degL[nl];
            deg[gn] = dg;
            const unsigned* c = &cnt8[nl * 8];
#pragma unroll
            for (int h = 0; h < 4; ++h) {
                float m = -3.4e38f;
#pragma unroll
                for (int tt = 0; tt < 8; ++tt)
                    if (c[tt]) m = fmaxf(m, se[tt * 4 + h]);
                float s = 0.f;
#pragma unroll
                for (int tt = 0; tt < 8; ++tt)
                    if (c[tt]) s += (float)c[tt] * expf(se[tt * 4 + h] - m);
                stats[(size_t)gn * 8 + h] = m;
                stats[(size_t)gn * 8 + 4 + h] = dg ? (1.0f / s) : 0.0f;
            }
        }
    }
    __syncthreads();
    for (unsigned i = r0 + tid; i < r1; i += 256) {
        unsigned en = csr2[i];
        unsigned nlo = (en >> 20) & 511u;
        unsigned tt = (en >> 17) & 7u;
        unsigned pos = r0 + atomicAdd(&curL[nlo], 1u);
        csr[pos] = (en & 0x1FFFFu) | (tt << 20);
    }
}

// K5: attn_out (E,H,4,1) — LDS-staged so all global stores are lane-contiguous
__global__ __launch_bounds__(256) void k_attn_out(const int* __restrict__ e_feat,
                                                  const int* __restrict__ dst,
                                                  const float* __restrict__ emb,
                                                  const float* __restrict__ stats,
                                                  float4* __restrict__ ao, int E) {
    __shared__ float av[4 * 257];
    int tid = threadIdx.x;
    int e = blockIdx.x * 256 + tid;
    float a0 = 0.f, a1 = 0.f, a2 = 0.f, a3 = 0.f;
    if (e < E) {
        int tt = e_feat[e];
        int d = dst[e];
        const float4* st4 = (const float4*)(stats + (size_t)d * 8);
        float4 m4 = st4[0], i4 = st4[1];
        float4 ee = *(const float4*)(emb + tt * 4);
        a0 = expf(ee.x - m4.x) * i4.x;
        a1 = expf(ee.y - m4.y) * i4.y;
        a2 = expf(ee.z - m4.z) * i4.z;
        a3 = expf(ee.w - m4.w) * i4.w;
    }
    av[0 * 257 + tid] = a0;
    av[1 * 257 + tid] = a1;
    av[2 * 257 + tid] = a2;
    av[3 * 257 + tid] = a3;
    __syncthreads();
    size_t base = (size_t)blockIdx.x * 1024;   // float4 index
    size_t lim = (size_t)E * 4;
#pragma unroll
    for (int r = 0; r < 4; ++r) {
        size_t g = base + r * 256 + tid;
        if (g < lim) {
            int gl = r * 256 + tid;         // block-local float4 idx
            float v = av[(gl & 3) * 257 + (gl >> 2)];
            ao[g] = make_float4(v, v, v, v);
        }
    }
}

// K6: ft = featb @ Wb^T, all-bf16 I/O. W staged in LDS (swizzled), A-fragments
// direct from global (ushort8, no conversion). Epilogue via LDS -> wide stores.
__global__ __launch_bounds__(256) void k_gemm_mfma(const unsigned short* __restrict__ featb,
                                                   const unsigned short* __restrict__ Wb,
                                                   unsigned short* __restrict__ ftb, int N) {
    __shared__ unsigned short Sb[128 * 136];  // 34 KB: W (swizzled), then out-tile
    int tid = threadIdx.x;
    int row0 = blockIdx.x * 128;

    // ---- stage Wb: bf16, swizzled (byte ^= (row&7)<<4) ----
#pragma unroll
    for (int it = 0; it < 8; ++it) {
        int idx = it * 2048 + tid * 8;
        int r = idx >> 7, c = idx & 127;
        ushort8 v = *(const ushort8*)(Wb + idx);
        *(ushort8*)((char*)Sb + (((unsigned)(r * 256 + c * 2)) ^ (unsigned)((r & 7) << 4))) = v;
    }
    __syncthreads();

    int wv = tid >> 6, lane = tid & 63;
    int rl = lane & 15;
    unsigned swz = (unsigned)((lane & 7) << 4);
    int kq = (lane >> 4) * 16;          // LDS byte offset of this lane's k-octet
    int ko = (lane >> 4) * 8;           // element offset of k-octet

    int ra0 = row0 + wv * 32 + rl;
    int ra1 = ra0 + 16;
    bool v0 = ra0 < N, v1 = ra1 < N;
    const unsigned short* ap0 = featb + (size_t)ra0 * 128 + ko;
    const unsigned short* ap1 = featb + (size_t)ra1 * 128 + ko;

    f32x4 acc[2][8];
#pragma unroll
    for (int rt = 0; rt < 2; ++rt)
#pragma unroll
        for (int jt = 0; jt < 8; ++jt)
            acc[rt][jt] = (f32x4){0.f, 0.f, 0.f, 0.f};

    const char* Bb = (const char*)Sb;
#pragma unroll
    for (int kk = 0; kk < 4; ++kk) {
        int kb = kk * 64 + kq;
        short8 a[2], bfr[8];
        ushort8 z = (ushort8){0,0,0,0,0,0,0,0};
        a[0] = __builtin_bit_cast(short8, v0 ? *(const ushort8*)(ap0 + kk * 32) : z);
        a[1] = __builtin_bit_cast(short8, v1 ? *(const ushort8*)(ap1 + kk * 32) : z);
#pragma unroll
        for (int jt = 0; jt < 8; ++jt)
            bfr[jt] = *(const short8*)(Bb + (((unsigned)((jt * 16 + rl) * 256 + kb)) ^ swz));
#pragma unroll
        for (int rt = 0; rt < 2; ++rt)
#pragma unroll
            for (int jt = 0; jt < 8; ++jt)
                acc[rt][jt] = __builtin_amdgcn_mfma_f32_16x16x32_bf16(a[rt], bfr[jt], acc[rt][jt], 0, 0, 0);
    }

    // ---- epilogue via LDS: W region dead; overwrite with out tile ----
    __syncthreads();
#pragma unroll
    for (int rt = 0; rt < 2; ++rt) {
        int rbase = wv * 32 + rt * 16 + ((lane >> 4) << 2);
#pragma unroll
        for (int jt = 0; jt < 8; ++jt) {
            int col = jt * 16 + rl;
#pragma unroll
            for (int rg = 0; rg < 4; ++rg)
                Sb[(rbase + rg) * 136 + col] = f2bf(acc[rt][jt][rg]);
        }
    }
    __syncthreads();
#pragma unroll
    for (int g = 0; g < 8; ++g) {
        int rloc = g * 16 + (tid >> 4);
        int cc = (tid & 15) * 8;
        int gr = row0 + rloc;
        if (gr < N) {
            ushort8 v = *(const ushort8*)(&Sb[rloc * 136 + cc]);
            *(ushort8*)(ftb + (size_t)gr * 128 + cc) = v;
        }
    }
}

// K7: aggregate: wave per node; csr chunk loaded once per 64 edges (coalesced),
// entries broadcast via shfl -> independent back-to-back ft row loads.
__global__ __launch_bounds__(256) void k_agg(const unsigned* __restrict__ csr,
                                             const unsigned* __restrict__ offs,
                                             const unsigned* __restrict__ deg,
                                             const float* __restrict__ stats,
                                             const float* __restrict__ emb,
                                             const unsigned* __restrict__ ftu,  // bf16 pairs
                                             float* __restrict__ rst, int N) {
    __shared__ float wl[4 * 32];
    int tid = threadIdx.x;
    int wv = tid >> 6, lane = tid & 63;
    int n = blockIdx.x * 4 + wv;
    n = __builtin_amdgcn_readfirstlane(n);
    if (n < N && lane < 32) {
        int tt = lane >> 2, hh = lane & 3;
        float m = stats[(size_t)n * 8 + hh];
        float is = stats[(size_t)n * 8 + 4 + hh];
        wl[wv * 32 + lane] = expf(emb[tt * 4 + hh] - m) * is;
    }
    __syncthreads();
    if (n >= N) return;
    unsigned o = offs[n], dg = deg[n];
    int h = lane >> 4;
    const float* wlh = wl + wv * 32 + h;
    float accx = 0.f, accy = 0.f;
    for (unsigned kb = 0; kb < dg; kb += 64) {
        unsigned rem = dg - kb; if (rem > 64) rem = 64;
        unsigned centry = 0;
        if (lane < (int)rem) centry = csr[o + kb + lane];
        unsigned j = 0;
        for (; j + 8 <= rem; j += 8) {
            unsigned f[8]; float a[8];
#pragma unroll
            for (int jj = 0; jj < 8; ++jj) {
                unsigned e = __shfl(centry, (int)(j + jj), 64);
                f[jj] = ftu[(size_t)(e & 0xFFFFFu) * 64 + lane];
                a[jj] = wlh[(e >> 20) * 4];
            }
#pragma unroll
            for (int jj = 0; jj < 8; ++jj) {
                accx = fmaf(a[jj], __builtin_bit_cast(float, f[jj] << 16), accx);
                accy = fmaf(a[jj], __builtin_bit_cast(float, f[jj] & 0xFFFF0000u), accy);
            }
        }
        for (; j < rem; ++j) {
            unsigned e = __shfl(centry, (int)j, 64);
            unsigned f0 = ftu[(size_t)(e & 0xFFFFFu) * 64 + lane];
            float a0 = wlh[(e >> 20) * 4];
            accx = fmaf(a0, __builtin_bit_cast(float, f0 << 16), accx);
            accy = fmaf(a0, __builtin_bit_cast(float, f0 & 0xFFFF0000u), accy);
        }
    }
    ((float2*)rst)[(size_t)n * 64 + lane] = make_float2(accx, accy);
}

extern "C" void kernel_launch(void* const* d_in, const int* in_sizes, int n_in,
                              void* d_out, int out_size, void* d_ws, size_t ws_size,
                              hipStream_t stream) {
    const float* feat = (const float*)d_in[0];
    const float* W = (const float*)d_in[1];
    const float* emb = (const float*)d_in[2];
    const int* e_feat = (const int*)d_in[3];
    const int* src = (const int*)d_in[4];
    const int* dst = (const int*)d_in[5];
    int N = in_sizes[0] / 128;
    int E = in_sizes[3];
    int nbuk = (N + 511) >> 9;
    long nf = (long)N * 128;
    long nw = (long)in_sizes[1];   // 16384

    char* ws = (char*)d_ws;
    size_t off = 0;
    auto alloc = [&](size_t bytes) {
        void* p = ws + off;
        off = (off + bytes + 255) & ~(size_t)255;
        return p;
    };
    unsigned short* featb = (unsigned short*)alloc((size_t)nf * 2);
    unsigned short* Wb = (unsigned short*)alloc((size_t)nw * 2);
    unsigned short* ftb = (unsigned short*)alloc((size_t)N * 128 * 2);
    float* stats = (float*)alloc((size_t)N * 8 * 4);
    unsigned* deg = (unsigned*)alloc((size_t)N * 4);
    unsigned* offs = (unsigned*)alloc((size_t)N * 4);
    unsigned* csr = (unsigned*)alloc((size_t)E * 4);
    unsigned* csr2 = (unsigned*)alloc((size_t)E * 4);
    unsigned* gcnt = (unsigned*)alloc(256 * 4);
    unsigned* gbase = (unsigned*)alloc(256 * 4);
    unsigned* gcur = (unsigned*)alloc(256 * 4);

    float* rst = (float*)d_out;
    float4* ao = (float4*)((float*)d_out + (size_t)N * 128);

    hipMemsetAsync(gcnt, 0, 256 * 4, stream);

    long ncvt = (nf + nw) / 8;
    k_cvt<<<(int)((ncvt + 255) / 256), 256, 0, stream>>>(feat, W, featb, Wb, nf, nw);
    k_bcnt<<<(E + 2047) / 2048, 256, 0, stream>>>(dst, gcnt, E);
    k_bscan<<<1, 256, 0, stream>>>(gcnt, gbase, gcur);
    k_part<<<(E + 4095) / 4096, 256, 0, stream>>>(src, dst, e_feat, gcur, csr2, E, nbuk);
    k_bsort2<<<nbuk, 256, 0, stream>>>(csr2, gbase, gcnt, emb, csr, offs, deg, stats, N);
    k_gemm_mfma<<<(N + 127) / 128, 256, 0, stream>>>(featb, Wb, ftb, N);
    k_attn_out<<<(E + 255) / 256, 256, 0, stream>>>(e_feat, dst, emb, stats, ao, E);
    k_agg<<<(N + 3) / 4, 256, 0, stream>>>(csr, offs, deg, stats, emb, (const unsigned*)ftb, rst, N);
}

// Round 10
// 178.691 us; speedup vs baseline: 1.1251x; 1.1195x over previous
//
#include <hip/hip_runtime.h>

// ---------------- constants for this problem ----------------
// N_NODES=100000, N_EDGES=1600000, IN_FEATS=128, H=4, D=32, HD=128, NUM_ETYPES=8, DROP_BLOCKS=4
// Bucket = 512 consecutive dst nodes (nbuk = ceil(N/512) = 196).
// csr2 entry: src[0:17) | etype[17:20) | (dst&511)[20:29)
// csr  entry: src[0:20) | etype[20:23)

typedef short short8 __attribute__((ext_vector_type(8)));
typedef unsigned short ushort8 __attribute__((ext_vector_type(8)));
typedef float f32x4 __attribute__((ext_vector_type(4)));

__device__ inline unsigned short f2bf(float x) {
    unsigned u = __builtin_bit_cast(unsigned, x);
    u += 0x7FFFu + ((u >> 16) & 1u);   // RNE
    return (unsigned short)(u >> 16);
}

__device__ inline void nt_store4(float* p, float a, float b, float c, float d) {
    f32x4 v = (f32x4){a, b, c, d};
    __builtin_nontemporal_store(v, (f32x4*)p);
}

// K1: per-chunk bucket histogram, NON-atomic output (no global memset needed)
__global__ __launch_bounds__(256) void k_bcnt(const int* __restrict__ dst,
                                              unsigned* __restrict__ gpart, int E) {
    __shared__ unsigned l[256];
    int tid = threadIdx.x;
    l[tid] = 0;
    __syncthreads();
    int base = blockIdx.x * 4096;
#pragma unroll
    for (int j = 0; j < 16; ++j) {
        int e = base + j * 256 + tid;
        if (e < E) atomicAdd(&l[(unsigned)dst[e] >> 9], 1u);
    }
    __syncthreads();
    gpart[blockIdx.x * 256 + tid] = l[tid];
}

// K2: column-reduce partials + exclusive scan (single block)
__global__ __launch_bounds__(256) void k_bscan(const unsigned* __restrict__ gpart,
                                               int nchunk,
                                               unsigned* __restrict__ gbase,
                                               unsigned* __restrict__ gcur) {
    __shared__ unsigned s[256];
    int t = threadIdx.x;
    unsigned sum = 0;
    int r = 0;
    for (; r + 4 <= nchunk; r += 4) {
        unsigned a0 = gpart[(r + 0) * 256 + t];
        unsigned a1 = gpart[(r + 1) * 256 + t];
        unsigned a2 = gpart[(r + 2) * 256 + t];
        unsigned a3 = gpart[(r + 3) * 256 + t];
        sum += a0 + a1 + a2 + a3;
    }
    for (; r < nchunk; ++r) sum += gpart[r * 256 + t];
    unsigned orig = sum;
    s[t] = sum;
    __syncthreads();
    for (int of = 1; of < 256; of <<= 1) {
        unsigned v = (t >= of) ? s[t - of] : 0u;
        __syncthreads();
        s[t] += v;
        __syncthreads();
    }
    unsigned eb = s[t] - orig;
    gbase[t] = eb;
    gcur[t] = eb;
}

// K3: LDS-staged partition. After this, gcur[b] = bucket END.
__global__ __launch_bounds__(256) void k_part(const int* __restrict__ src,
                                              const int* __restrict__ dst,
                                              const int* __restrict__ ef,
                                              unsigned* __restrict__ gcur,
                                              unsigned* __restrict__ csr2,
                                              int E, int nbuk) {
    __shared__ unsigned lcnt[256];
    __shared__ unsigned lbase[256];
    __shared__ unsigned lcur[256];
    __shared__ unsigned gw2[256];
    __shared__ unsigned stp[4096];
    __shared__ unsigned short stb[4096];
    int tid = threadIdx.x;
    lcnt[tid] = 0;
    __syncthreads();

    int cb = blockIdx.x * 4096;
    int cc = E - cb; if (cc > 4096) cc = 4096;

    unsigned pay[16];
    unsigned short bk[16];
#pragma unroll
    for (int j = 0; j < 16; ++j) {
        int idx = j * 256 + tid;
        if (idx < cc) {
            int e = cb + idx;
            unsigned d = (unsigned)dst[e];
            pay[j] = (unsigned)src[e] | ((unsigned)ef[e] << 17) | ((d & 511u) << 20);
            bk[j] = (unsigned short)(d >> 9);
            atomicAdd(&lcnt[bk[j]], 1u);
        }
    }
    __syncthreads();
    lbase[tid] = lcnt[tid];
    __syncthreads();
    for (int of = 1; of < 256; of <<= 1) {
        unsigned v = (tid >= of) ? lbase[tid - of] : 0u;
        __syncthreads();
        lbase[tid] += v;
        __syncthreads();
    }
    unsigned eb = lbase[tid] - lcnt[tid];
    __syncthreads();
    lbase[tid] = eb;
    lcur[tid] = eb;
    __syncthreads();
#pragma unroll
    for (int j = 0; j < 16; ++j) {
        int idx = j * 256 + tid;
        if (idx < cc) {
            unsigned lpos = atomicAdd(&lcur[bk[j]], 1u);
            stp[lpos] = pay[j];
            stb[lpos] = bk[j];
        }
    }
    if (tid < nbuk && lcnt[tid]) gw2[tid] = atomicAdd(&gcur[tid], lcnt[tid]);
    __syncthreads();
#pragma unroll
    for (int j = 0; j < 16; ++j) {
        int i = j * 256 + tid;
        if (i < cc) {
            unsigned b = stb[i];
            csr2[gw2[b] + (i - lbase[b])] = stp[i];
        }
    }
}

// K4: per-bucket: count (node,etype), scan node degrees -> offs/deg/stats,
// then counting-sort into final node-grouped CSR. gend[b] = bucket END index.
__global__ __launch_bounds__(256) void k_bsort2(const unsigned* __restrict__ csr2,
                                                const unsigned* __restrict__ gbase,
                                                const unsigned* __restrict__ gend,
                                                const float* __restrict__ emb,
                                                unsigned* __restrict__ csr,
                                                unsigned* __restrict__ offs,
                                                unsigned* __restrict__ deg,
                                                float* __restrict__ stats, int N) {
    __shared__ unsigned cnt8[512 * 8];   // 16 KB
    __shared__ unsigned degL[512];
    __shared__ unsigned offsL[512];
    __shared__ unsigned curL[512];
    __shared__ unsigned tmp[256];
    __shared__ float se[32];
    int b = blockIdx.x, tid = threadIdx.x;
    if (tid < 32) se[tid] = emb[tid];
#pragma unroll
    for (int i = 0; i < 16; ++i) cnt8[i * 256 + tid] = 0u;
    __syncthreads();
    unsigned r0 = gbase[b], r1 = gend[b];
    for (unsigned i = r0 + tid; i < r1; i += 256) {
        unsigned en = csr2[i];
        atomicAdd(&cnt8[((en >> 20) & 511u) * 8u + ((en >> 17) & 7u)], 1u);
    }
    __syncthreads();
    int n0 = tid * 2, n1 = tid * 2 + 1;
    unsigned d0 = 0, d1 = 0;
#pragma unroll
    for (int k = 0; k < 8; ++k) { d0 += cnt8[n0 * 8 + k]; d1 += cnt8[n1 * 8 + k]; }
    degL[n0] = d0; degL[n1] = d1;
    tmp[tid] = d0 + d1;
    __syncthreads();
    for (int of = 1; of < 256; of <<= 1) {
        unsigned v = (tid >= of) ? tmp[tid - of] : 0u;
        __syncthreads();
        tmp[tid] += v;
        __syncthreads();
    }
    unsigned eb = tmp[tid] - (d0 + d1);
    offsL[n0] = eb;        curL[n0] = eb;
    offsL[n1] = eb + d0;   curL[n1] = eb + d0;
#pragma unroll
    for (int q = 0; q < 2; ++q) {
        int nl = tid * 2 + q;
        int gn = b * 512 + nl;
        if (gn < N) {
            offs[gn] = r0 + offsL[nl];
            unsigned dg = degL[nl];
            deg[gn] = dg;
            const unsigned* c = &cnt8[nl * 8];
#pragma unroll
            for (int h = 0; h < 4; ++h) {
                float m = -3.4e38f;
#pragma unroll
                for (int tt = 0; tt < 8; ++tt)
                    if (c[tt]) m = fmaxf(m, se[tt * 4 + h]);
                float s = 0.f;
#pragma unroll
                for (int tt = 0; tt < 8; ++tt)
                    if (c[tt]) s += (float)c[tt] * expf(se[tt * 4 + h] - m);
                stats[(size_t)gn * 8 + h] = m;
                stats[(size_t)gn * 8 + 4 + h] = dg ? (1.0f / s) : 0.0f;
            }
        }
    }
    __syncthreads();
    for (unsigned i = r0 + tid; i < r1; i += 256) {
        unsigned en = csr2[i];
        unsigned nlo = (en >> 20) & 511u;
        unsigned tt = (en >> 17) & 7u;
        unsigned pos = r0 + atomicAdd(&curL[nlo], 1u);
        csr[pos] = (en & 0x1FFFFu) | (tt << 20);
    }
}

// K5: attn_out (E,H,4,1) — LDS-staged, nontemporal lane-contiguous stores
__global__ __launch_bounds__(256) void k_attn_out(const int* __restrict__ e_feat,
                                                  const int* __restrict__ dst,
                                                  const float* __restrict__ emb,
                                                  const float* __restrict__ stats,
                                                  float* __restrict__ ao, int E) {
    __shared__ float av[4 * 257];
    int tid = threadIdx.x;
    int e = blockIdx.x * 256 + tid;
    float a0 = 0.f, a1 = 0.f, a2 = 0.f, a3 = 0.f;
    if (e < E) {
        int tt = e_feat[e];
        int d = dst[e];
        const float4* st4 = (const float4*)(stats + (size_t)d * 8);
        float4 m4 = st4[0], i4 = st4[1];
        float4 ee = *(const float4*)(emb + tt * 4);
        a0 = expf(ee.x - m4.x) * i4.x;
        a1 = expf(ee.y - m4.y) * i4.y;
        a2 = expf(ee.z - m4.z) * i4.z;
        a3 = expf(ee.w - m4.w) * i4.w;
    }
    av[0 * 257 + tid] = a0;
    av[1 * 257 + tid] = a1;
    av[2 * 257 + tid] = a2;
    av[3 * 257 + tid] = a3;
    __syncthreads();
    size_t base = (size_t)blockIdx.x * 1024;   // float4 index
    size_t lim = (size_t)E * 4;
#pragma unroll
    for (int r = 0; r < 4; ++r) {
        size_t g = base + r * 256 + tid;
        if (g < lim) {
            int gl = r * 256 + tid;
            float v = av[(gl & 3) * 257 + (gl >> 2)];
            nt_store4(ao + g * 4, v, v, v, v);
        }
    }
}

// K6: ft = feat @ W^T via bf16 MFMA; A direct from global (fp32->bf16 in reg);
// W staged in LDS (swizzled). Epilogue via LDS -> wide contiguous stores.
__global__ __launch_bounds__(256) void k_gemm_mfma(const float* __restrict__ feat,
                                                   const float* __restrict__ W,
                                                   unsigned short* __restrict__ ftb, int N) {
    __shared__ unsigned short Sb[128 * 136];  // 34 KB
    int tid = threadIdx.x;
    int row0 = blockIdx.x * 128;

#pragma unroll
    for (int it = 0; it < 16; ++it) {
        int i = it * 1024 + tid * 4;
        int r = i >> 7, c = i & 127;
        unsigned swz = (unsigned)((r & 7) << 4);
        float4 w4 = *(const float4*)(W + i);
        ushort4 wb;
        wb.x = f2bf(w4.x); wb.y = f2bf(w4.y); wb.z = f2bf(w4.z); wb.w = f2bf(w4.w);
        *(ushort4*)((char*)Sb + (((unsigned)(r * 256 + c * 2)) ^ swz)) = wb;
    }
    __syncthreads();

    int wv = tid >> 6, lane = tid & 63;
    int rl = lane & 15;
    unsigned swz = (unsigned)((lane & 7) << 4);
    int kq = (lane >> 4) * 16;
    int ko = (lane >> 4) * 8;

    int ra0 = row0 + wv * 32 + rl;
    int ra1 = ra0 + 16;
    bool v0 = ra0 < N, v1 = ra1 < N;
    const float* ap0 = feat + (size_t)ra0 * 128 + ko;
    const float* ap1 = feat + (size_t)ra1 * 128 + ko;

    f32x4 acc[2][8];
#pragma unroll
    for (int rt = 0; rt < 2; ++rt)
#pragma unroll
        for (int jt = 0; jt < 8; ++jt)
            acc[rt][jt] = (f32x4){0.f, 0.f, 0.f, 0.f};

    const char* Bb = (const char*)Sb;
#pragma unroll
    for (int kk = 0; kk < 4; ++kk) {
        int kb = kk * 64 + kq;
        short8 a[2], bfr[8];
#pragma unroll
        for (int rt = 0; rt < 2; ++rt) {
            const float* ap = rt ? ap1 : ap0;
            bool v = rt ? v1 : v0;
            float4 lo = make_float4(0.f, 0.f, 0.f, 0.f), hi = lo;
            if (v) { lo = *(const float4*)(ap + kk * 32); hi = *(const float4*)(ap + kk * 32 + 4); }
            short8 t;
            t[0] = (short)f2bf(lo.x); t[1] = (short)f2bf(lo.y);
            t[2] = (short)f2bf(lo.z); t[3] = (short)f2bf(lo.w);
            t[4] = (short)f2bf(hi.x); t[5] = (short)f2bf(hi.y);
            t[6] = (short)f2bf(hi.z); t[7] = (short)f2bf(hi.w);
            a[rt] = t;
        }
#pragma unroll
        for (int jt = 0; jt < 8; ++jt)
            bfr[jt] = *(const short8*)(Bb + (((unsigned)((jt * 16 + rl) * 256 + kb)) ^ swz));
#pragma unroll
        for (int rt = 0; rt < 2; ++rt)
#pragma unroll
            for (int jt = 0; jt < 8; ++jt)
                acc[rt][jt] = __builtin_amdgcn_mfma_f32_16x16x32_bf16(a[rt], bfr[jt], acc[rt][jt], 0, 0, 0);
    }

    __syncthreads();
#pragma unroll
    for (int rt = 0; rt < 2; ++rt) {
        int rbase = wv * 32 + rt * 16 + ((lane >> 4) << 2);
#pragma unroll
        for (int jt = 0; jt < 8; ++jt) {
            int col = jt * 16 + rl;
#pragma unroll
            for (int rg = 0; rg < 4; ++rg)
                Sb[(rbase + rg) * 136 + col] = f2bf(acc[rt][jt][rg]);
        }
    }
    __syncthreads();
#pragma unroll
    for (int g = 0; g < 8; ++g) {
        int rloc = g * 16 + (tid >> 4);
        int cc = (tid & 15) * 8;
        int gr = row0 + rloc;
        if (gr < N) {
            ushort8 v = *(const ushort8*)(&Sb[rloc * 136 + cc]);
            *(ushort8*)(ftb + (size_t)gr * 128 + cc) = v;
        }
    }
}

// K7: aggregate: wave per node; 4 edges per wave-instruction (uint4 gather,
// 16 lanes per 256 B ft row, edge slot = lane>>4). Fold slots via shfl_xor.
__global__ __launch_bounds__(256) void k_agg(const unsigned* __restrict__ csr,
                                             const unsigned* __restrict__ offs,
                                             const unsigned* __restrict__ deg,
                                             const float* __restrict__ stats,
                                             const float* __restrict__ emb,
                                             const uint4* __restrict__ ft4,
                                             float* __restrict__ rst, int N) {
    __shared__ float wl[4 * 32];
    int tid = threadIdx.x;
    int wv = tid >> 6, lane = tid & 63;
    int n = blockIdx.x * 4 + wv;
    n = __builtin_amdgcn_readfirstlane(n);
    if (n < N && lane < 32) {
        int tt = lane >> 2, hh = lane & 3;
        float m = stats[(size_t)n * 8 + hh];
        float is = stats[(size_t)n * 8 + 4 + hh];
        wl[wv * 32 + lane] = expf(emb[tt * 4 + hh] - m) * is;
    }
    __syncthreads();
    if (n >= N) return;
    unsigned o = offs[n], dg = deg[n];
    int cl = lane & 15;
    int es = lane >> 4;
    int h = cl >> 2;
    const float* wlh = wl + wv * 32 + h;
    float acc[8];
#pragma unroll
    for (int i = 0; i < 8; ++i) acc[i] = 0.f;

    for (unsigned kb = 0; kb < dg; kb += 64) {
        unsigned rem = dg - kb; if (rem > 64) rem = 64;
        unsigned centry = 0;
        if (lane < (int)rem) centry = csr[o + kb + lane];
        unsigned g = 0;
        for (; g + 16 <= rem; g += 16) {
            uint4 f[4]; float a[4];
#pragma unroll
            for (int q = 0; q < 4; ++q) {
                unsigned e = __shfl(centry, (int)(g + q * 4 + es), 64);
                f[q] = ft4[(size_t)(e & 0xFFFFFu) * 16 + cl];
                a[q] = wlh[(e >> 20) * 4];
            }
#pragma unroll
            for (int q = 0; q < 4; ++q) {
                acc[0] = fmaf(a[q], __builtin_bit_cast(float, f[q].x << 16), acc[0]);
                acc[1] = fmaf(a[q], __builtin_bit_cast(float, f[q].x & 0xFFFF0000u), acc[1]);
                acc[2] = fmaf(a[q], __builtin_bit_cast(float, f[q].y << 16), acc[2]);
                acc[3] = fmaf(a[q], __builtin_bit_cast(float, f[q].y & 0xFFFF0000u), acc[3]);
                acc[4] = fmaf(a[q], __builtin_bit_cast(float, f[q].z << 16), acc[4]);
                acc[5] = fmaf(a[q], __builtin_bit_cast(float, f[q].z & 0xFFFF0000u), acc[5]);
                acc[6] = fmaf(a[q], __builtin_bit_cast(float, f[q].w << 16), acc[6]);
                acc[7] = fmaf(a[q], __builtin_bit_cast(float, f[q].w & 0xFFFF0000u), acc[7]);
            }
        }
        for (; g < rem; g += 4) {
            int eidx = (int)g + es;
            bool valid = eidx < (int)rem;
            unsigned e = __shfl(centry, valid ? eidx : (int)g, 64);
            uint4 f = ft4[(size_t)(e & 0xFFFFFu) * 16 + cl];
            float a = valid ? wlh[(e >> 20) * 4] : 0.f;
            acc[0] = fmaf(a, __builtin_bit_cast(float, f.x << 16), acc[0]);
            acc[1] = fmaf(a, __builtin_bit_cast(float, f.x & 0xFFFF0000u), acc[1]);
            acc[2] = fmaf(a, __builtin_bit_cast(float, f.y << 16), acc[2]);
            acc[3] = fmaf(a, __builtin_bit_cast(float, f.y & 0xFFFF0000u), acc[3]);
            acc[4] = fmaf(a, __builtin_bit_cast(float, f.z << 16), acc[4]);
            acc[5] = fmaf(a, __builtin_bit_cast(float, f.z & 0xFFFF0000u), acc[5]);
            acc[6] = fmaf(a, __builtin_bit_cast(float, f.w << 16), acc[6]);
            acc[7] = fmaf(a, __builtin_bit_cast(float, f.w & 0xFFFF0000u), acc[7]);
        }
    }
#pragma unroll
    for (int i = 0; i < 8; ++i) {
        acc[i] += __shfl_xor(acc[i], 16, 64);
        acc[i] += __shfl_xor(acc[i], 32, 64);
    }
    if (lane < 16) {
        float* op = rst + (size_t)n * 128 + cl * 8;
        nt_store4(op, acc[0], acc[1], acc[2], acc[3]);
        nt_store4(op + 4, acc[4], acc[5], acc[6], acc[7]);
    }
}

extern "C" void kernel_launch(void* const* d_in, const int* in_sizes, int n_in,
                              void* d_out, int out_size, void* d_ws, size_t ws_size,
                              hipStream_t stream) {
    const float* feat = (const float*)d_in[0];
    const float* W = (const float*)d_in[1];
    const float* emb = (const float*)d_in[2];
    const int* e_feat = (const int*)d_in[3];
    const int* src = (const int*)d_in[4];
    const int* dst = (const int*)d_in[5];
    int N = in_sizes[0] / 128;
    int E = in_sizes[3];
    int nbuk = (N + 511) >> 9;
    int nchunk = (E + 4095) / 4096;

    char* ws = (char*)d_ws;
    size_t off = 0;
    auto alloc = [&](size_t bytes) {
        void* p = ws + off;
        off = (off + bytes + 255) & ~(size_t)255;
        return p;
    };
    unsigned short* ftb = (unsigned short*)alloc((size_t)N * 128 * 2);
    float* stats = (float*)alloc((size_t)N * 8 * 4);
    unsigned* deg = (unsigned*)alloc((size_t)N * 4);
    unsigned* offs = (unsigned*)alloc((size_t)N * 4);
    unsigned* csr = (unsigned*)alloc((size_t)E * 4);
    unsigned* csr2 = (unsigned*)alloc((size_t)E * 4);
    unsigned* gpart = (unsigned*)alloc((size_t)nchunk * 256 * 4);
    unsigned* gbase = (unsigned*)alloc(256 * 4);
    unsigned* gcur = (unsigned*)alloc(256 * 4);

    float* rst = (float*)d_out;
    float* ao = (float*)d_out + (size_t)N * 128;

    k_bcnt<<<nchunk, 256, 0, stream>>>(dst, gpart, E);
    k_bscan<<<1, 256, 0, stream>>>(gpart, nchunk, gbase, gcur);
    k_part<<<nchunk, 256, 0, stream>>>(src, dst, e_feat, gcur, csr2, E, nbuk);
    k_bsort2<<<nbuk, 256, 0, stream>>>(csr2, gbase, gcur, emb, csr, offs, deg, stats, N);
    k_attn_out<<<(E + 255) / 256, 256, 0, stream>>>(e_feat, dst, emb, stats, ao, E);
    k_gemm_mfma<<<(N + 127) / 128, 256, 0, stream>>>(feat, W, ftb, N);
    k_agg<<<(N + 3) / 4, 256, 0, stream>>>(csr, offs, deg, stats, emb, (const uint4*)ftb, rst, N);
}

// Round 11
// 165.300 us; speedup vs baseline: 1.2162x; 1.0810x over previous
//
#include <hip/hip_runtime.h>

// ---------------- constants for this problem ----------------
// N_NODES=100000, N_EDGES=1600000, IN_FEATS=128, H=4, D=32, HD=128, NUM_ETYPES=8, DROP_BLOCKS=4
// Bucket = 512 consecutive dst nodes (nbuk = ceil(N/512) = 196).
// csr2 entry: src[0:17) | etype[17:20) | (dst&511)[20:29)
// csr  entry: src[0:20) | etype[20:23)

typedef short short8 __attribute__((ext_vector_type(8)));
typedef unsigned short ushort8 __attribute__((ext_vector_type(8)));
typedef float f32x4 __attribute__((ext_vector_type(4)));

__device__ inline unsigned short f2bf(float x) {
    unsigned u = __builtin_bit_cast(unsigned, x);
    u += 0x7FFFu + ((u >> 16) & 1u);   // RNE
    return (unsigned short)(u >> 16);
}

__device__ inline void nt_store4(float* p, float a, float b, float c, float d) {
    f32x4 v = (f32x4){a, b, c, d};
    __builtin_nontemporal_store(v, (f32x4*)p);
}

// K1: per-chunk bucket histogram, NON-atomic output (no global memset needed)
__global__ __launch_bounds__(256) void k_bcnt(const int* __restrict__ dst,
                                              unsigned* __restrict__ gpart, int E) {
    __shared__ unsigned l[256];
    int tid = threadIdx.x;
    l[tid] = 0;
    __syncthreads();
    int base = blockIdx.x * 4096;
#pragma unroll
    for (int j = 0; j < 16; ++j) {
        int e = base + j * 256 + tid;
        if (e < E) atomicAdd(&l[(unsigned)dst[e] >> 9], 1u);
    }
    __syncthreads();
    gpart[blockIdx.x * 256 + tid] = l[tid];
}

// K2: column-reduce partials + exclusive scan (single block)
__global__ __launch_bounds__(256) void k_bscan(const unsigned* __restrict__ gpart,
                                               int nchunk,
                                               unsigned* __restrict__ gbase,
                                               unsigned* __restrict__ gcur) {
    __shared__ unsigned s[256];
    int t = threadIdx.x;
    unsigned sum = 0;
    int r = 0;
    for (; r + 4 <= nchunk; r += 4) {
        unsigned a0 = gpart[(r + 0) * 256 + t];
        unsigned a1 = gpart[(r + 1) * 256 + t];
        unsigned a2 = gpart[(r + 2) * 256 + t];
        unsigned a3 = gpart[(r + 3) * 256 + t];
        sum += a0 + a1 + a2 + a3;
    }
    for (; r < nchunk; ++r) sum += gpart[r * 256 + t];
    unsigned orig = sum;
    s[t] = sum;
    __syncthreads();
    for (int of = 1; of < 256; of <<= 1) {
        unsigned v = (t >= of) ? s[t - of] : 0u;
        __syncthreads();
        s[t] += v;
        __syncthreads();
    }
    unsigned eb = s[t] - orig;
    gbase[t] = eb;
    gcur[t] = eb;
}

// K3 (FUSED): blocks [0, partBlocks) = LDS-staged partition;
//             blocks [partBlocks, ...) = bf16 MFMA GEMM.
// Both share one 34 KB LDS buffer (part carves 28 KB from it).
__global__ __launch_bounds__(256) void k_partgemm(
        const int* __restrict__ src, const int* __restrict__ dst,
        const int* __restrict__ ef, unsigned* __restrict__ gcur,
        unsigned* __restrict__ csr2, int E, int nbuk, int partBlocks,
        const float* __restrict__ feat, const float* __restrict__ W,
        unsigned short* __restrict__ ftb, int N) {
    __shared__ unsigned short Sb[128 * 136];  // 34 KB union
    int tid = threadIdx.x;

    if (blockIdx.x < (unsigned)partBlocks) {
        // ---------------- partition path ----------------
        unsigned* lcnt = (unsigned*)Sb;
        unsigned* lbase = lcnt + 256;
        unsigned* lcur = lbase + 256;
        unsigned* gw2 = lcur + 256;
        unsigned* stp = gw2 + 256;
        unsigned short* stb = (unsigned short*)(stp + 4096);
        int bid = blockIdx.x;
        lcnt[tid] = 0;
        __syncthreads();

        int cb = bid * 4096;
        int cc = E - cb; if (cc > 4096) cc = 4096;

        unsigned pay[16];
        unsigned short bk[16];
#pragma unroll
        for (int j = 0; j < 16; ++j) {
            int idx = j * 256 + tid;
            if (idx < cc) {
                int e = cb + idx;
                unsigned d = (unsigned)dst[e];
                pay[j] = (unsigned)src[e] | ((unsigned)ef[e] << 17) | ((d & 511u) << 20);
                bk[j] = (unsigned short)(d >> 9);
                atomicAdd(&lcnt[bk[j]], 1u);
            }
        }
        __syncthreads();
        lbase[tid] = lcnt[tid];
        __syncthreads();
        for (int of = 1; of < 256; of <<= 1) {
            unsigned v = (tid >= of) ? lbase[tid - of] : 0u;
            __syncthreads();
            lbase[tid] += v;
            __syncthreads();
        }
        unsigned eb = lbase[tid] - lcnt[tid];
        __syncthreads();
        lbase[tid] = eb;
        lcur[tid] = eb;
        __syncthreads();
#pragma unroll
        for (int j = 0; j < 16; ++j) {
            int idx = j * 256 + tid;
            if (idx < cc) {
                unsigned lpos = atomicAdd(&lcur[bk[j]], 1u);
                stp[lpos] = pay[j];
                stb[lpos] = bk[j];
            }
        }
        if (tid < nbuk && lcnt[tid]) gw2[tid] = atomicAdd(&gcur[tid], lcnt[tid]);
        __syncthreads();
#pragma unroll
        for (int j = 0; j < 16; ++j) {
            int i = j * 256 + tid;
            if (i < cc) {
                unsigned b = stb[i];
                csr2[gw2[b] + (i - lbase[b])] = stp[i];
            }
        }
        return;
    }

    // ---------------- GEMM path ----------------
    int row0 = (blockIdx.x - partBlocks) * 128;

#pragma unroll
    for (int it = 0; it < 16; ++it) {
        int i = it * 1024 + tid * 4;
        int r = i >> 7, c = i & 127;
        unsigned swz = (unsigned)((r & 7) << 4);
        float4 w4 = *(const float4*)(W + i);
        ushort4 wb;
        wb.x = f2bf(w4.x); wb.y = f2bf(w4.y); wb.z = f2bf(w4.z); wb.w = f2bf(w4.w);
        *(ushort4*)((char*)Sb + (((unsigned)(r * 256 + c * 2)) ^ swz)) = wb;
    }
    __syncthreads();

    int wv = tid >> 6, lane = tid & 63;
    int rl = lane & 15;
    unsigned swz = (unsigned)((lane & 7) << 4);
    int kq = (lane >> 4) * 16;
    int ko = (lane >> 4) * 8;

    int ra0 = row0 + wv * 32 + rl;
    int ra1 = ra0 + 16;
    bool v0 = ra0 < N, v1 = ra1 < N;
    const float* ap0 = feat + (size_t)ra0 * 128 + ko;
    const float* ap1 = feat + (size_t)ra1 * 128 + ko;

    f32x4 acc[2][8];
#pragma unroll
    for (int rt = 0; rt < 2; ++rt)
#pragma unroll
        for (int jt = 0; jt < 8; ++jt)
            acc[rt][jt] = (f32x4){0.f, 0.f, 0.f, 0.f};

    const char* Bb = (const char*)Sb;
#pragma unroll
    for (int kk = 0; kk < 4; ++kk) {
        int kb = kk * 64 + kq;
        short8 a[2], bfr[8];
#pragma unroll
        for (int rt = 0; rt < 2; ++rt) {
            const float* ap = rt ? ap1 : ap0;
            bool v = rt ? v1 : v0;
            float4 lo = make_float4(0.f, 0.f, 0.f, 0.f), hi = lo;
            if (v) { lo = *(const float4*)(ap + kk * 32); hi = *(const float4*)(ap + kk * 32 + 4); }
            short8 t;
            t[0] = (short)f2bf(lo.x); t[1] = (short)f2bf(lo.y);
            t[2] = (short)f2bf(lo.z); t[3] = (short)f2bf(lo.w);
            t[4] = (short)f2bf(hi.x); t[5] = (short)f2bf(hi.y);
            t[6] = (short)f2bf(hi.z); t[7] = (short)f2bf(hi.w);
            a[rt] = t;
        }
#pragma unroll
        for (int jt = 0; jt < 8; ++jt)
            bfr[jt] = *(const short8*)(Bb + (((unsigned)((jt * 16 + rl) * 256 + kb)) ^ swz));
#pragma unroll
        for (int rt = 0; rt < 2; ++rt)
#pragma unroll
            for (int jt = 0; jt < 8; ++jt)
                acc[rt][jt] = __builtin_amdgcn_mfma_f32_16x16x32_bf16(a[rt], bfr[jt], acc[rt][jt], 0, 0, 0);
    }

    __syncthreads();
#pragma unroll
    for (int rt = 0; rt < 2; ++rt) {
        int rbase = wv * 32 + rt * 16 + ((lane >> 4) << 2);
#pragma unroll
        for (int jt = 0; jt < 8; ++jt) {
            int col = jt * 16 + rl;
#pragma unroll
            for (int rg = 0; rg < 4; ++rg)
                Sb[(rbase + rg) * 136 + col] = f2bf(acc[rt][jt][rg]);
        }
    }
    __syncthreads();
#pragma unroll
    for (int g = 0; g < 8; ++g) {
        int rloc = g * 16 + (tid >> 4);
        int cc = (tid & 15) * 8;
        int gr = row0 + rloc;
        if (gr < N) {
            ushort8 v = *(const ushort8*)(&Sb[rloc * 136 + cc]);
            *(ushort8*)(ftb + (size_t)gr * 128 + cc) = v;
        }
    }
}

// K4: per-bucket: count (node,etype), scan node degrees -> offs/deg/stats,
// then counting-sort into final node-grouped CSR. gend[b] = bucket END index.
__global__ __launch_bounds__(256) void k_bsort2(const unsigned* __restrict__ csr2,
                                                const unsigned* __restrict__ gbase,
                                                const unsigned* __restrict__ gend,
                                                const float* __restrict__ emb,
                                                unsigned* __restrict__ csr,
                                                unsigned* __restrict__ offs,
                                                unsigned* __restrict__ deg,
                                                float* __restrict__ stats, int N) {
    __shared__ unsigned cnt8[512 * 8];   // 16 KB
    __shared__ unsigned degL[512];
    __shared__ unsigned offsL[512];
    __shared__ unsigned curL[512];
    __shared__ unsigned tmp[256];
    __shared__ float se[32];
    int b = blockIdx.x, tid = threadIdx.x;
    if (tid < 32) se[tid] = emb[tid];
#pragma unroll
    for (int i = 0; i < 16; ++i) cnt8[i * 256 + tid] = 0u;
    __syncthreads();
    unsigned r0 = gbase[b], r1 = gend[b];
    for (unsigned i = r0 + tid; i < r1; i += 256) {
        unsigned en = csr2[i];
        atomicAdd(&cnt8[((en >> 20) & 511u) * 8u + ((en >> 17) & 7u)], 1u);
    }
    __syncthreads();
    int n0 = tid * 2, n1 = tid * 2 + 1;
    unsigned d0 = 0, d1 = 0;
#pragma unroll
    for (int k = 0; k < 8; ++k) { d0 += cnt8[n0 * 8 + k]; d1 += cnt8[n1 * 8 + k]; }
    degL[n0] = d0; degL[n1] = d1;
    tmp[tid] = d0 + d1;
    __syncthreads();
    for (int of = 1; of < 256; of <<= 1) {
        unsigned v = (tid >= of) ? tmp[tid - of] : 0u;
        __syncthreads();
        tmp[tid] += v;
        __syncthreads();
    }
    unsigned eb = tmp[tid] - (d0 + d1);
    offsL[n0] = eb;        curL[n0] = eb;
    offsL[n1] = eb + d0;   curL[n1] = eb + d0;
#pragma unroll
    for (int q = 0; q < 2; ++q) {
        int nl = tid * 2 + q;
        int gn = b * 512 + nl;
        if (gn < N) {
            offs[gn] = r0 + offsL[nl];
            unsigned dg = degL[nl];
            deg[gn] = dg;
            const unsigned* c = &cnt8[nl * 8];
#pragma unroll
            for (int h = 0; h < 4; ++h) {
                float m = -3.4e38f;
#pragma unroll
                for (int tt = 0; tt < 8; ++tt)
                    if (c[tt]) m = fmaxf(m, se[tt * 4 + h]);
                float s = 0.f;
#pragma unroll
                for (int tt = 0; tt < 8; ++tt)
                    if (c[tt]) s += (float)c[tt] * expf(se[tt * 4 + h] - m);
                stats[(size_t)gn * 8 + h] = m;
                stats[(size_t)gn * 8 + 4 + h] = dg ? (1.0f / s) : 0.0f;
            }
        }
    }
    __syncthreads();
    for (unsigned i = r0 + tid; i < r1; i += 256) {
        unsigned en = csr2[i];
        unsigned nlo = (en >> 20) & 511u;
        unsigned tt = (en >> 17) & 7u;
        unsigned pos = r0 + atomicAdd(&curL[nlo], 1u);
        csr[pos] = (en & 0x1FFFFu) | (tt << 20);
    }
}

// K5 (FUSED): blocks [0, aggBlocks) = aggregate; rest = attn_out.
__global__ __launch_bounds__(256) void k_aggattn(
        const unsigned* __restrict__ csr, const unsigned* __restrict__ offs,
        const unsigned* __restrict__ deg, const float* __restrict__ stats,
        const float* __restrict__ emb, const uint4* __restrict__ ft4,
        float* __restrict__ rst, int N, int aggBlocks,
        const int* __restrict__ e_feat, const int* __restrict__ dst,
        float* __restrict__ ao, int E) {
    __shared__ float sbuf[4 * 257];   // attn needs 4*257; agg uses first 128
    int tid = threadIdx.x;

    if (blockIdx.x >= (unsigned)aggBlocks) {
        // ---------------- attn_out path ----------------
        int bid = blockIdx.x - aggBlocks;
        int e = bid * 256 + tid;
        float a0 = 0.f, a1 = 0.f, a2 = 0.f, a3 = 0.f;
        if (e < E) {
            int tt = e_feat[e];
            int d = dst[e];
            const float4* st4 = (const float4*)(stats + (size_t)d * 8);
            float4 m4 = st4[0], i4 = st4[1];
            float4 ee = *(const float4*)(emb + tt * 4);
            a0 = expf(ee.x - m4.x) * i4.x;
            a1 = expf(ee.y - m4.y) * i4.y;
            a2 = expf(ee.z - m4.z) * i4.z;
            a3 = expf(ee.w - m4.w) * i4.w;
        }
        sbuf[0 * 257 + tid] = a0;
        sbuf[1 * 257 + tid] = a1;
        sbuf[2 * 257 + tid] = a2;
        sbuf[3 * 257 + tid] = a3;
        __syncthreads();
        size_t base = (size_t)bid * 1024;   // float4 index
        size_t lim = (size_t)E * 4;
#pragma unroll
        for (int r = 0; r < 4; ++r) {
            size_t g = base + r * 256 + tid;
            if (g < lim) {
                int gl = r * 256 + tid;
                float v = sbuf[(gl & 3) * 257 + (gl >> 2)];
                nt_store4(ao + g * 4, v, v, v, v);
            }
        }
        return;
    }

    // ---------------- aggregate path ----------------
    float* wl = sbuf;
    int wv = tid >> 6, lane = tid & 63;
    int n = blockIdx.x * 4 + wv;
    n = __builtin_amdgcn_readfirstlane(n);
    if (n < N && lane < 32) {
        int tt = lane >> 2, hh = lane & 3;
        float m = stats[(size_t)n * 8 + hh];
        float is = stats[(size_t)n * 8 + 4 + hh];
        wl[wv * 32 + lane] = expf(emb[tt * 4 + hh] - m) * is;
    }
    __syncthreads();
    if (n >= N) return;
    unsigned o = offs[n], dg = deg[n];
    int cl = lane & 15;
    int es = lane >> 4;
    int h = cl >> 2;
    const float* wlh = wl + wv * 32 + h;
    float acc[8];
#pragma unroll
    for (int i = 0; i < 8; ++i) acc[i] = 0.f;

    for (unsigned kb = 0; kb < dg; kb += 64) {
        unsigned rem = dg - kb; if (rem > 64) rem = 64;
        unsigned centry = 0;
        if (lane < (int)rem) centry = csr[o + kb + lane];
        unsigned g = 0;
        for (; g + 16 <= rem; g += 16) {
            uint4 f[4]; float a[4];
#pragma unroll
            for (int q = 0; q < 4; ++q) {
                unsigned e = __shfl(centry, (int)(g + q * 4 + es), 64);
                f[q] = ft4[(size_t)(e & 0xFFFFFu) * 16 + cl];
                a[q] = wlh[(e >> 20) * 4];
            }
#pragma unroll
            for (int q = 0; q < 4; ++q) {
                acc[0] = fmaf(a[q], __builtin_bit_cast(float, f[q].x << 16), acc[0]);
                acc[1] = fmaf(a[q], __builtin_bit_cast(float, f[q].x & 0xFFFF0000u), acc[1]);
                acc[2] = fmaf(a[q], __builtin_bit_cast(float, f[q].y << 16), acc[2]);
                acc[3] = fmaf(a[q], __builtin_bit_cast(float, f[q].y & 0xFFFF0000u), acc[3]);
                acc[4] = fmaf(a[q], __builtin_bit_cast(float, f[q].z << 16), acc[4]);
                acc[5] = fmaf(a[q], __builtin_bit_cast(float, f[q].z & 0xFFFF0000u), acc[5]);
                acc[6] = fmaf(a[q], __builtin_bit_cast(float, f[q].w << 16), acc[6]);
                acc[7] = fmaf(a[q], __builtin_bit_cast(float, f[q].w & 0xFFFF0000u), acc[7]);
            }
        }
        for (; g < rem; g += 4) {
            int eidx = (int)g + es;
            bool valid = eidx < (int)rem;
            unsigned e = __shfl(centry, valid ? eidx : (int)g, 64);
            uint4 f = ft4[(size_t)(e & 0xFFFFFu) * 16 + cl];
            float a = valid ? wlh[(e >> 20) * 4] : 0.f;
            acc[0] = fmaf(a, __builtin_bit_cast(float, f.x << 16), acc[0]);
            acc[1] = fmaf(a, __builtin_bit_cast(float, f.x & 0xFFFF0000u), acc[1]);
            acc[2] = fmaf(a, __builtin_bit_cast(float, f.y << 16), acc[2]);
            acc[3] = fmaf(a, __builtin_bit_cast(float, f.y & 0xFFFF0000u), acc[3]);
            acc[4] = fmaf(a, __builtin_bit_cast(float, f.z << 16), acc[4]);
            acc[5] = fmaf(a, __builtin_bit_cast(float, f.z & 0xFFFF0000u), acc[5]);
            acc[6] = fmaf(a, __builtin_bit_cast(float, f.w << 16), acc[6]);
            acc[7] = fmaf(a, __builtin_bit_cast(float, f.w & 0xFFFF0000u), acc[7]);
        }
    }
#pragma unroll
    for (int i = 0; i < 8; ++i) {
        acc[i] += __shfl_xor(acc[i], 16, 64);
        acc[i] += __shfl_xor(acc[i], 32, 64);
    }
    if (lane < 16) {
        float* op = rst + (size_t)n * 128 + cl * 8;
        nt_store4(op, acc[0], acc[1], acc[2], acc[3]);
        nt_store4(op + 4, acc[4], acc[5], acc[6], acc[7]);
    }
}

extern "C" void kernel_launch(void* const* d_in, const int* in_sizes, int n_in,
                              void* d_out, int out_size, void* d_ws, size_t ws_size,
                              hipStream_t stream) {
    const float* feat = (const float*)d_in[0];
    const float* W = (const float*)d_in[1];
    const float* emb = (const float*)d_in[2];
    const int* e_feat = (const int*)d_in[3];
    const int* src = (const int*)d_in[4];
    const int* dst = (const int*)d_in[5];
    int N = in_sizes[0] / 128;
    int E = in_sizes[3];
    int nbuk = (N + 511) >> 9;
    int nchunk = (E + 4095) / 4096;        // 391
    int gemmBlocks = (N + 127) / 128;      // 782
    int aggBlocks = (N + 3) / 4;           // 25000
    int attnBlocks = (E + 255) / 256;      // 6250

    char* ws = (char*)d_ws;
    size_t off = 0;
    auto alloc = [&](size_t bytes) {
        void* p = ws + off;
        off = (off + bytes + 255) & ~(size_t)255;
        return p;
    };
    unsigned short* ftb = (unsigned short*)alloc((size_t)N * 128 * 2);
    float* stats = (float*)alloc((size_t)N * 8 * 4);
    unsigned* deg = (unsigned*)alloc((size_t)N * 4);
    unsigned* offs = (unsigned*)alloc((size_t)N * 4);
    unsigned* csr = (unsigned*)alloc((size_t)E * 4);
    unsigned* csr2 = (unsigned*)alloc((size_t)E * 4);
    unsigned* gpart = (unsigned*)alloc((size_t)nchunk * 256 * 4);
    unsigned* gbase = (unsigned*)alloc(256 * 4);
    unsigned* gcur = (unsigned*)alloc(256 * 4);

    float* rst = (float*)d_out;
    float* ao = (float*)d_out + (size_t)N * 128;

    k_bcnt<<<nchunk, 256, 0, stream>>>(dst, gpart, E);
    k_bscan<<<1, 256, 0, stream>>>(gpart, nchunk, gbase, gcur);
    k_partgemm<<<nchunk + gemmBlocks, 256, 0, stream>>>(
        src, dst, e_feat, gcur, csr2, E, nbuk, nchunk, feat, W, ftb, N);
    k_bsort2<<<nbuk, 256, 0, stream>>>(csr2, gbase, gcur, emb, csr, offs, deg, stats, N);
    k_aggattn<<<aggBlocks + attnBlocks, 256, 0, stream>>>(
        csr, offs, deg, stats, emb, (const uint4*)ftb, rst, N, aggBlocks,
        e_feat, dst, ao, E);
}

// Round 12
// 164.613 us; speedup vs baseline: 1.2213x; 1.0042x over previous
//
#include <hip/hip_runtime.h>

// ---------------- constants for this problem ----------------
// N_NODES=100000, N_EDGES=1600000, IN_FEATS=128, H=4, D=32, HD=128, NUM_ETYPES=8, DROP_BLOCKS=4
// Bucket = 512 consecutive dst nodes (nbuk = ceil(N/512) = 196).
// csr2 entry: src[0:17) | etype[17:20) | (dst&511)[20:29)
// csr  entry: src[0:20) | etype[20:23)

typedef short short8 __attribute__((ext_vector_type(8)));
typedef unsigned short ushort8 __attribute__((ext_vector_type(8)));
typedef float f32x4 __attribute__((ext_vector_type(4)));

__device__ inline unsigned short f2bf(float x) {
    unsigned u = __builtin_bit_cast(unsigned, x);
    u += 0x7FFFu + ((u >> 16) & 1u);   // RNE
    return (unsigned short)(u >> 16);
}

__device__ inline short8 cvt8(float4 lo, float4 hi) {
    short8 t;
    t[0] = (short)f2bf(lo.x); t[1] = (short)f2bf(lo.y);
    t[2] = (short)f2bf(lo.z); t[3] = (short)f2bf(lo.w);
    t[4] = (short)f2bf(hi.x); t[5] = (short)f2bf(hi.y);
    t[6] = (short)f2bf(hi.z); t[7] = (short)f2bf(hi.w);
    return t;
}

__device__ inline void nt_store4(float* p, float a, float b, float c, float d) {
    f32x4 v = (f32x4){a, b, c, d};
    __builtin_nontemporal_store(v, (f32x4*)p);
}

// K1: per-chunk bucket histogram (non-atomic partials, no memset needed).
// Blocks 0..7 additionally convert W (16384 fp32) -> Wb bf16.
__global__ __launch_bounds__(256) void k_bcnt(const int* __restrict__ dst,
                                              unsigned* __restrict__ gpart, int E,
                                              const float* __restrict__ W,
                                              unsigned short* __restrict__ Wb) {
    __shared__ unsigned l[256];
    int tid = threadIdx.x;
    if (blockIdx.x < 8) {
        int i = blockIdx.x * 2048 + tid * 8;
        float4 lo = *(const float4*)(W + i);
        float4 hi = *(const float4*)(W + i + 4);
        *(ushort8*)(Wb + i) = __builtin_bit_cast(ushort8, cvt8(lo, hi));
    }
    l[tid] = 0;
    __syncthreads();
    int base = blockIdx.x * 4096;
#pragma unroll
    for (int j = 0; j < 16; ++j) {
        int e = base + j * 256 + tid;
        if (e < E) atomicAdd(&l[(unsigned)dst[e] >> 9], 1u);
    }
    __syncthreads();
    gpart[blockIdx.x * 256 + tid] = l[tid];
}

// K2: column-reduce partials + exclusive scan (single block)
__global__ __launch_bounds__(256) void k_bscan(const unsigned* __restrict__ gpart,
                                               int nchunk,
                                               unsigned* __restrict__ gbase,
                                               unsigned* __restrict__ gcur) {
    __shared__ unsigned s[256];
    int t = threadIdx.x;
    unsigned sum = 0;
    int r = 0;
    for (; r + 4 <= nchunk; r += 4) {
        unsigned a0 = gpart[(r + 0) * 256 + t];
        unsigned a1 = gpart[(r + 1) * 256 + t];
        unsigned a2 = gpart[(r + 2) * 256 + t];
        unsigned a3 = gpart[(r + 3) * 256 + t];
        sum += a0 + a1 + a2 + a3;
    }
    for (; r < nchunk; ++r) sum += gpart[r * 256 + t];
    unsigned orig = sum;
    s[t] = sum;
    __syncthreads();
    for (int of = 1; of < 256; of <<= 1) {
        unsigned v = (t >= of) ? s[t - of] : 0u;
        __syncthreads();
        s[t] += v;
        __syncthreads();
    }
    unsigned eb = s[t] - orig;
    gbase[t] = eb;
    gcur[t] = eb;
}

// K3 (FUSED): blocks [0, partBlocks) = LDS-staged partition;
//             blocks [partBlocks, ...) = bf16 MFMA GEMM (register-pipelined).
__global__ __launch_bounds__(256) void k_partgemm(
        const int* __restrict__ src, const int* __restrict__ dst,
        const int* __restrict__ ef, unsigned* __restrict__ gcur,
        unsigned* __restrict__ csr2, int E, int nbuk, int partBlocks,
        const float* __restrict__ feat, const unsigned short* __restrict__ Wb,
        unsigned short* __restrict__ ftb, int N) {
    __shared__ unsigned short Sb[128 * 136];  // 34 KB union
    int tid = threadIdx.x;

    if (blockIdx.x < (unsigned)partBlocks) {
        // ---------------- partition path ----------------
        unsigned* lcnt = (unsigned*)Sb;
        unsigned* lbase = lcnt + 256;
        unsigned* lcur = lbase + 256;
        unsigned* gw2 = lcur + 256;
        unsigned* stp = gw2 + 256;
        unsigned short* stb = (unsigned short*)(stp + 4096);
        int bid = blockIdx.x;
        lcnt[tid] = 0;
        __syncthreads();

        int cb = bid * 4096;
        int cc = E - cb; if (cc > 4096) cc = 4096;

        unsigned pay[16];
        unsigned short bk[16];
#pragma unroll
        for (int j = 0; j < 16; ++j) {
            int idx = j * 256 + tid;
            if (idx < cc) {
                int e = cb + idx;
                unsigned d = (unsigned)dst[e];
                pay[j] = (unsigned)src[e] | ((unsigned)ef[e] << 17) | ((d & 511u) << 20);
                bk[j] = (unsigned short)(d >> 9);
                atomicAdd(&lcnt[bk[j]], 1u);
            }
        }
        __syncthreads();
        lbase[tid] = lcnt[tid];
        __syncthreads();
        for (int of = 1; of < 256; of <<= 1) {
            unsigned v = (tid >= of) ? lbase[tid - of] : 0u;
            __syncthreads();
            lbase[tid] += v;
            __syncthreads();
        }
        unsigned eb = lbase[tid] - lcnt[tid];
        __syncthreads();
        lbase[tid] = eb;
        lcur[tid] = eb;
        __syncthreads();
#pragma unroll
        for (int j = 0; j < 16; ++j) {
            int idx = j * 256 + tid;
            if (idx < cc) {
                unsigned lpos = atomicAdd(&lcur[bk[j]], 1u);
                stp[lpos] = pay[j];
                stb[lpos] = bk[j];
            }
        }
        if (tid < nbuk && lcnt[tid]) gw2[tid] = atomicAdd(&gcur[tid], lcnt[tid]);
        __syncthreads();
#pragma unroll
        for (int j = 0; j < 16; ++j) {
            int i = j * 256 + tid;
            if (i < cc) {
                unsigned b = stb[i];
                csr2[gw2[b] + (i - lbase[b])] = stp[i];
            }
        }
        return;
    }

    // ---------------- GEMM path (register-pipelined, bounded live ranges) ----
    int row0 = (blockIdx.x - partBlocks) * 128;

    // stage Wb (bf16): 8 x ushort8, swizzled (byte ^= (row&7)<<4)
#pragma unroll
    for (int it = 0; it < 8; ++it) {
        int idx = it * 2048 + tid * 8;
        int r = idx >> 7, c = idx & 127;
        ushort8 v = *(const ushort8*)(Wb + idx);
        *(ushort8*)((char*)Sb + (((unsigned)(r * 256 + c * 2)) ^ (unsigned)((r & 7) << 4))) = v;
    }
    __syncthreads();

    int wv = tid >> 6, lane = tid & 63;
    int rl = lane & 15;
    unsigned swz = (unsigned)((lane & 7) << 4);
    int kq = (lane >> 4) * 16;          // LDS byte offset of this lane's k-octet
    int ko = (lane >> 4) * 8;           // element offset of k-octet

    int ra0 = row0 + wv * 32 + rl;
    int ra1 = ra0 + 16;
    int rc0 = ra0 < N - 1 ? ra0 : N - 1;   // clamp: branchless loads, garbage discarded at store
    int rc1 = ra1 < N - 1 ? ra1 : N - 1;
    const float* ap0 = feat + (size_t)rc0 * 128 + ko;
    const float* ap1 = feat + (size_t)rc1 * 128 + ko;

    f32x4 acc[2][8];
#pragma unroll
    for (int rt = 0; rt < 2; ++rt)
#pragma unroll
        for (int jt = 0; jt < 8; ++jt)
            acc[rt][jt] = (f32x4){0.f, 0.f, 0.f, 0.f};

    const char* Bb = (const char*)Sb;

    // prefetch kk=0 A
    float4 l0 = *(const float4*)(ap0);
    float4 h0 = *(const float4*)(ap0 + 4);
    float4 l1 = *(const float4*)(ap1);
    float4 h1 = *(const float4*)(ap1 + 4);

#pragma unroll 1
    for (int kk = 0; kk < 4; ++kk) {
        short8 a0 = cvt8(l0, h0);
        short8 a1 = cvt8(l1, h1);
        int kn = kk < 3 ? kk + 1 : 3;   // clamped prefetch (no branch)
        l0 = *(const float4*)(ap0 + kn * 32);
        h0 = *(const float4*)(ap0 + kn * 32 + 4);
        l1 = *(const float4*)(ap1 + kn * 32);
        h1 = *(const float4*)(ap1 + kn * 32 + 4);
        int kb = kk * 64 + kq;
#pragma unroll
        for (int jt = 0; jt < 8; ++jt) {
            short8 bj = *(const short8*)(Bb + (((unsigned)((jt * 16 + rl) * 256 + kb)) ^ swz));
            acc[0][jt] = __builtin_amdgcn_mfma_f32_16x16x32_bf16(a0, bj, acc[0][jt], 0, 0, 0);
            acc[1][jt] = __builtin_amdgcn_mfma_f32_16x16x32_bf16(a1, bj, acc[1][jt], 0, 0, 0);
        }
    }

    // epilogue via LDS (W region dead) -> wide contiguous stores
    __syncthreads();
#pragma unroll
    for (int rt = 0; rt < 2; ++rt) {
        int rbase = wv * 32 + rt * 16 + ((lane >> 4) << 2);
#pragma unroll
        for (int jt = 0; jt < 8; ++jt) {
            int col = jt * 16 + rl;
#pragma unroll
            for (int rg = 0; rg < 4; ++rg)
                Sb[(rbase + rg) * 136 + col] = f2bf(acc[rt][jt][rg]);
        }
    }
    __syncthreads();
#pragma unroll
    for (int g = 0; g < 8; ++g) {
        int rloc = g * 16 + (tid >> 4);
        int cc = (tid & 15) * 8;
        int gr = row0 + rloc;
        if (gr < N) {
            ushort8 v = *(const ushort8*)(&Sb[rloc * 136 + cc]);
            *(ushort8*)(ftb + (size_t)gr * 128 + cc) = v;
        }
    }
}

// K4: per-bucket: count (node,etype), scan node degrees -> offs/deg/stats,
// then counting-sort into final node-grouped CSR. gend[b] = bucket END index.
__global__ __launch_bounds__(256) void k_bsort2(const unsigned* __restrict__ csr2,
                                                const unsigned* __restrict__ gbase,
                                                const unsigned* __restrict__ gend,
                                                const float* __restrict__ emb,
                                                unsigned* __restrict__ csr,
                                                unsigned* __restrict__ offs,
                                                unsigned* __restrict__ deg,
                                                float* __restrict__ stats, int N) {
    __shared__ unsigned cnt8[512 * 8];   // 16 KB
    __shared__ unsigned degL[512];
    __shared__ unsigned offsL[512];
    __shared__ unsigned curL[512];
    __shared__ unsigned tmp[256];
    __shared__ float se[32];
    int b = blockIdx.x, tid = threadIdx.x;
    if (tid < 32) se[tid] = emb[tid];
#pragma unroll
    for (int i = 0; i < 16; ++i) cnt8[i * 256 + tid] = 0u;
    __syncthreads();
    unsigned r0 = gbase[b], r1 = gend[b];
    for (unsigned i = r0 + tid; i < r1; i += 256) {
        unsigned en = csr2[i];
        atomicAdd(&cnt8[((en >> 20) & 511u) * 8u + ((en >> 17) & 7u)], 1u);
    }
    __syncthreads();
    int n0 = tid * 2, n1 = tid * 2 + 1;
    unsigned d0 = 0, d1 = 0;
#pragma unroll
    for (int k = 0; k < 8; ++k) { d0 += cnt8[n0 * 8 + k]; d1 += cnt8[n1 * 8 + k]; }
    degL[n0] = d0; degL[n1] = d1;
    tmp[tid] = d0 + d1;
    __syncthreads();
    for (int of = 1; of < 256; of <<= 1) {
        unsigned v = (tid >= of) ? tmp[tid - of] : 0u;
        __syncthreads();
        tmp[tid] += v;
        __syncthreads();
    }
    unsigned eb = tmp[tid] - (d0 + d1);
    offsL[n0] = eb;        curL[n0] = eb;
    offsL[n1] = eb + d0;   curL[n1] = eb + d0;
#pragma unroll
    for (int q = 0; q < 2; ++q) {
        int nl = tid * 2 + q;
        int gn = b * 512 + nl;
        if (gn < N) {
            offs[gn] = r0 + offsL[nl];
            unsigned dg = degL[nl];
            deg[gn] = dg;
            const unsigned* c = &cnt8[nl * 8];
#pragma unroll
            for (int h = 0; h < 4; ++h) {
                float m = -3.4e38f;
#pragma unroll
                for (int tt = 0; tt < 8; ++tt)
                    if (c[tt]) m = fmaxf(m, se[tt * 4 + h]);
                float s = 0.f;
#pragma unroll
                for (int tt = 0; tt < 8; ++tt)
                    if (c[tt]) s += (float)c[tt] * expf(se[tt * 4 + h] - m);
                stats[(size_t)gn * 8 + h] = m;
                stats[(size_t)gn * 8 + 4 + h] = dg ? (1.0f / s) : 0.0f;
            }
        }
    }
    __syncthreads();
    for (unsigned i = r0 + tid; i < r1; i += 256) {
        unsigned en = csr2[i];
        unsigned nlo = (en >> 20) & 511u;
        unsigned tt = (en >> 17) & 7u;
        unsigned pos = r0 + atomicAdd(&curL[nlo], 1u);
        csr[pos] = (en & 0x1FFFFu) | (tt << 20);
    }
}

// K5 (FUSED): blocks [0, aggBlocks) = aggregate; rest = attn_out.
__global__ __launch_bounds__(256) void k_aggattn(
        const unsigned* __restrict__ csr, const unsigned* __restrict__ offs,
        const unsigned* __restrict__ deg, const float* __restrict__ stats,
        const float* __restrict__ emb, const uint4* __restrict__ ft4,
        float* __restrict__ rst, int N, int aggBlocks,
        const int* __restrict__ e_feat, const int* __restrict__ dst,
        float* __restrict__ ao, int E) {
    __shared__ float sbuf[4 * 257];   // attn needs 4*257; agg uses first 128
    int tid = threadIdx.x;

    if (blockIdx.x >= (unsigned)aggBlocks) {
        // ---------------- attn_out path ----------------
        int bid = blockIdx.x - aggBlocks;
        int e = bid * 256 + tid;
        float a0 = 0.f, a1 = 0.f, a2 = 0.f, a3 = 0.f;
        if (e < E) {
            int tt = e_feat[e];
            int d = dst[e];
            const float4* st4 = (const float4*)(stats + (size_t)d * 8);
            float4 m4 = st4[0], i4 = st4[1];
            float4 ee = *(const float4*)(emb + tt * 4);
            a0 = expf(ee.x - m4.x) * i4.x;
            a1 = expf(ee.y - m4.y) * i4.y;
            a2 = expf(ee.z - m4.z) * i4.z;
            a3 = expf(ee.w - m4.w) * i4.w;
        }
        sbuf[0 * 257 + tid] = a0;
        sbuf[1 * 257 + tid] = a1;
        sbuf[2 * 257 + tid] = a2;
        sbuf[3 * 257 + tid] = a3;
        __syncthreads();
        size_t base = (size_t)bid * 1024;   // float4 index
        size_t lim = (size_t)E * 4;
#pragma unroll
        for (int r = 0; r < 4; ++r) {
            size_t g = base + r * 256 + tid;
            if (g < lim) {
                int gl = r * 256 + tid;
                float v = sbuf[(gl & 3) * 257 + (gl >> 2)];
                nt_store4(ao + g * 4, v, v, v, v);
            }
        }
        return;
    }

    // ---------------- aggregate path ----------------
    float* wl = sbuf;
    int wv = tid >> 6, lane = tid & 63;
    int n = blockIdx.x * 4 + wv;
    n = __builtin_amdgcn_readfirstlane(n);
    if (n < N && lane < 32) {
        int tt = lane >> 2, hh = lane & 3;
        float m = stats[(size_t)n * 8 + hh];
        float is = stats[(size_t)n * 8 + 4 + hh];
        wl[wv * 32 + lane] = expf(emb[tt * 4 + hh] - m) * is;
    }
    __syncthreads();
    if (n >= N) return;
    unsigned o = offs[n], dg = deg[n];
    int cl = lane & 15;
    int es = lane >> 4;
    int h = cl >> 2;
    const float* wlh = wl + wv * 32 + h;
    float acc[8];
#pragma unroll
    for (int i = 0; i < 8; ++i) acc[i] = 0.f;

    for (unsigned kb = 0; kb < dg; kb += 64) {
        unsigned rem = dg - kb; if (rem > 64) rem = 64;
        unsigned centry = 0;
        if (lane < (int)rem) centry = csr[o + kb + lane];
        unsigned g = 0;
        for (; g + 16 <= rem; g += 16) {
            uint4 f[4]; float a[4];
#pragma unroll
            for (int q = 0; q < 4; ++q) {
                unsigned e = __shfl(centry, (int)(g + q * 4 + es), 64);
                f[q] = ft4[(size_t)(e & 0xFFFFFu) * 16 + cl];
                a[q] = wlh[(e >> 20) * 4];
            }
#pragma unroll
            for (int q = 0; q < 4; ++q) {
                acc[0] = fmaf(a[q], __builtin_bit_cast(float, f[q].x << 16), acc[0]);
                acc[1] = fmaf(a[q], __builtin_bit_cast(float, f[q].x & 0xFFFF0000u), acc[1]);
                acc[2] = fmaf(a[q], __builtin_bit_cast(float, f[q].y << 16), acc[2]);
                acc[3] = fmaf(a[q], __builtin_bit_cast(float, f[q].y & 0xFFFF0000u), acc[3]);
                acc[4] = fmaf(a[q], __builtin_bit_cast(float, f[q].z << 16), acc[4]);
                acc[5] = fmaf(a[q], __builtin_bit_cast(float, f[q].z & 0xFFFF0000u), acc[5]);
                acc[6] = fmaf(a[q], __builtin_bit_cast(float, f[q].w << 16), acc[6]);
                acc[7] = fmaf(a[q], __builtin_bit_cast(float, f[q].w & 0xFFFF0000u), acc[7]);
            }
        }
        for (; g < rem; g += 4) {
            int eidx = (int)g + es;
            bool valid = eidx < (int)rem;
            unsigned e = __shfl(centry, valid ? eidx : (int)g, 64);
            uint4 f = ft4[(size_t)(e & 0xFFFFFu) * 16 + cl];
            float a = valid ? wlh[(e >> 20) * 4] : 0.f;
            acc[0] = fmaf(a, __builtin_bit_cast(float, f.x << 16), acc[0]);
            acc[1] = fmaf(a, __builtin_bit_cast(float, f.x & 0xFFFF0000u), acc[1]);
            acc[2] = fmaf(a, __builtin_bit_cast(float, f.y << 16), acc[2]);
            acc[3] = fmaf(a, __builtin_bit_cast(float, f.y & 0xFFFF0000u), acc[3]);
            acc[4] = fmaf(a, __builtin_bit_cast(float, f.z << 16), acc[4]);
            acc[5] = fmaf(a, __builtin_bit_cast(float, f.z & 0xFFFF0000u), acc[5]);
            acc[6] = fmaf(a, __builtin_bit_cast(float, f.w << 16), acc[6]);
            acc[7] = fmaf(a, __builtin_bit_cast(float, f.w & 0xFFFF0000u), acc[7]);
        }
    }
#pragma unroll
    for (int i = 0; i < 8; ++i) {
        acc[i] += __shfl_xor(acc[i], 16, 64);
        acc[i] += __shfl_xor(acc[i], 32, 64);
    }
    if (lane < 16) {
        float* op = rst + (size_t)n * 128 + cl * 8;
        nt_store4(op, acc[0], acc[1], acc[2], acc[3]);
        nt_store4(op + 4, acc[4], acc[5], acc[6], acc[7]);
    }
}

extern "C" void kernel_launch(void* const* d_in, const int* in_sizes, int n_in,
                              void* d_out, int out_size, void* d_ws, size_t ws_size,
                              hipStream_t stream) {
    const float* feat = (const float*)d_in[0];
    const float* W = (const float*)d_in[1];
    const float* emb = (const float*)d_in[2];
    const int* e_feat = (const int*)d_in[3];
    const int* src = (const int*)d_in[4];
    const int* dst = (const int*)d_in[5];
    int N = in_sizes[0] / 128;
    int E = in_sizes[3];
    int nbuk = (N + 511) >> 9;
    int nchunk = (E + 4095) / 4096;        // 391
    int gemmBlocks = (N + 127) / 128;      // 782
    int aggBlocks = (N + 3) / 4;           // 25000
    int attnBlocks = (E + 255) / 256;      // 6250

    char* ws = (char*)d_ws;
    size_t off = 0;
    auto alloc = [&](size_t bytes) {
        void* p = ws + off;
        off = (off + bytes + 255) & ~(size_t)255;
        return p;
    };
    unsigned short* ftb = (unsigned short*)alloc((size_t)N * 128 * 2);
    unsigned short* Wb = (unsigned short*)alloc((size_t)in_sizes[1] * 2);
    float* stats = (float*)alloc((size_t)N * 8 * 4);
    unsigned* deg = (unsigned*)alloc((size_t)N * 4);
    unsigned* offs = (unsigned*)alloc((size_t)N * 4);
    unsigned* csr = (unsigned*)alloc((size_t)E * 4);
    unsigned* csr2 = (unsigned*)alloc((size_t)E * 4);
    unsigned* gpart = (unsigned*)alloc((size_t)nchunk * 256 * 4);
    unsigned* gbase = (unsigned*)alloc(256 * 4);
    unsigned* gcur = (unsigned*)alloc(256 * 4);

    float* rst = (float*)d_out;
    float* ao = (float*)d_out + (size_t)N * 128;

    k_bcnt<<<nchunk, 256, 0, stream>>>(dst, gpart, E, W, Wb);
    k_bscan<<<1, 256, 0, stream>>>(gpart, nchunk, gbase, gcur);
    k_partgemm<<<nchunk + gemmBlocks, 256, 0, stream>>>(
        src, dst, e_feat, gcur, csr2, E, nbuk, nchunk, feat, Wb, ftb, N);
    k_bsort2<<<nbuk, 256, 0, stream>>>(csr2, gbase, gcur, emb, csr, offs, deg, stats, N);
    k_aggattn<<<aggBlocks + attnBlocks, 256, 0, stream>>>(
        csr, offs, deg, stats, emb, (const uint4*)ftb, rst, N, aggBlocks,
        e_feat, dst, ao, E);
}